// Round 5
// baseline (434.292 us; speedup 1.0000x reference)
//
#include <hip/hip_runtime.h>
#include <hip/hip_bf16.h>
#include <math.h>

#define NH   8
#define DHD  128
#define HIDN 512
#define CHK  64
#define NCH  32
#define MB   1048576ull

typedef unsigned short u16;
typedef unsigned int   u32;
typedef short s16x8 __attribute__((ext_vector_type(8)));
typedef float f32x4 __attribute__((ext_vector_type(4)));

#define MFMA(a,b,c) __builtin_amdgcn_mfma_f32_16x16x32_bf16((a),(b),(c),0,0,0)

__device__ __forceinline__ float bf2f(u16 v){ return __uint_as_float(((u32)v) << 16); }
__device__ __forceinline__ u16 f2bf(float f){
  u32 u = __float_as_uint(f);
  u += 0x7fffu + ((u >> 16) & 1u);
  return (u16)(u >> 16);
}
__device__ __forceinline__ u32 pack2(float a, float b){
  return (u32)f2bf(a) | ((u32)f2bf(b) << 16);
}
__device__ __forceinline__ float waveRedSum(float v){
  #pragma unroll
  for (int off = 32; off; off >>= 1) v += __shfl_xor(v, off);
  return v;
}
// swizzles: 16B-slot XOR within a row-stripe (bank-conflict-free frag reads)
__device__ __forceinline__ int swzb(int row, int colb){ return colb ^ ((row & 7) << 4); }
// for the [64][1024B] a-tile: also spread row-bit3,4 into byte-bits 5,6 so
// column gathers (tok varying by 8 via lg) hit distinct bank octets
__device__ __forceinline__ int swza(int row, int colb){
  return colb ^ ((row & 7) << 4) ^ (((row >> 3) & 3) << 5);
}

// ---------------- prep ----------------

__global__ __launch_bounds__(256) void k_rmsnorm(const float* __restrict__ x,
    const float* __restrict__ wst, const float* __restrict__ wrt,
    u16* __restrict__ s_bf, u16* __restrict__ r_bf){
  int row = blockIdx.x, t = threadIdx.x;
  float4 v = ((const float4*)(x + (size_t)row*1024))[t];
  float ss = v.x*v.x + v.y*v.y + v.z*v.z + v.w*v.w;
  ss = waveRedSum(ss);
  __shared__ float red[4];
  int wv = t >> 6, ln = t & 63;
  if (ln == 0) red[wv] = ss;
  __syncthreads();
  float rr = rsqrtf((red[0]+red[1]+red[2]+red[3])*(1.f/1024.f) + 1e-6f);
  float4 a = ((const float4*)wst)[t];
  float4 b = ((const float4*)wrt)[t];
  uint2 so = make_uint2(pack2(v.x*rr*a.x, v.y*rr*a.y), pack2(v.z*rr*a.z, v.w*rr*a.w));
  uint2 ro = make_uint2(pack2(v.x*rr*b.x, v.y*rr*b.y), pack2(v.z*rr*b.z, v.w*rr*b.w));
  *(uint2*)(s_bf + (size_t)row*1024 + t*4) = so;
  *(uint2*)(r_bf + (size_t)row*1024 + t*4) = ro;
}

__global__ __launch_bounds__(256) void k_pool(const u16* __restrict__ s_bf, float* __restrict__ pooled){
  int c = blockIdx.x; int d = blockIdx.y*256 + threadIdx.x;
  float acc = 0.f;
  for (int tt = 0; tt < 64; ++tt) acc += bf2f(s_bf[((size_t)c*64+tt)*1024 + d]);
  pooled[(size_t)c*1024 + d] = acc * (1.f/64.f);
}

__global__ __launch_bounds__(256) void k_lrgate(const u16* __restrict__ s_bf, const u16* __restrict__ r_bf,
    const float* __restrict__ Wstep, const float* __restrict__ bstep,
    const float* __restrict__ gateW,
    float* __restrict__ lrc, float* __restrict__ gate){
  int wv = threadIdx.x >> 6, ln = threadIdx.x & 63;
  int tok = blockIdx.x*4 + wv;
  const u16* srow = s_bf + (size_t)tok*1024;
  const u16* rrow = r_bf + (size_t)tok*1024;
  for (int o = 0; o < 16; ++o){
    int h = o & 7;
    const u16* src = (o < 8) ? srow : rrow;
    const float* W = (o < 8) ? Wstep : gateW;
    float acc = 0.f;
    for (int k = ln; k < 1024; k += 64) acc += bf2f(src[k])*W[(size_t)k*8+h];
    acc = waveRedSum(acc);
    if (ln == 0){
      if (o < 8){
        float v = 1.f/(1.f+expf(-(acc + bstep[h])));
        lrc[((size_t)h*NCH + (tok>>6))*CHK + (tok&63)] = v;
      } else {
        gate[(size_t)tok*8 + h] = 1.f/(1.f+expf(-acc));
      }
    }
  }
}

__global__ __launch_bounds__(64) void k_momdec(const float* __restrict__ pooled,
    const float* __restrict__ Wmom, const float* __restrict__ bmom,
    const float* __restrict__ Wdec, const float* __restrict__ bdec,
    float* __restrict__ momb, float* __restrict__ decb){
  int c = blockIdx.x, ln = threadIdx.x;
  const float* prow = pooled + (size_t)c*1024;
  for (int o = 0; o < 16; ++o){
    int h = o & 7;
    const float* W = (o < 8) ? Wmom : Wdec;
    float acc = 0.f;
    for (int k = ln; k < 1024; k += 64) acc += prow[k]*W[(size_t)k*8+h];
    acc = waveRedSum(acc);
    if (ln == 0){
      float bb = (o < 8) ? bmom[h] : bdec[h];
      float v = 1.f/(1.f+expf(-(acc+bb)));
      if (o < 8) momb[h*NCH + c] = v; else decb[h*NCH + c] = v;
    }
  }
}

// batched transpose f32 -> bf16 : in (b,R,C) -> out (b,C,R)
__global__ __launch_bounds__(256) void k_trf(const float* __restrict__ in, u16* __restrict__ out, int R, int C){
  __shared__ u16 tile[32][34];
  int b = blockIdx.z; int c0 = blockIdx.x*32, r0 = blockIdx.y*32;
  int tx = threadIdx.x & 31, ty = threadIdx.x >> 5;
  const float* ib = in + (size_t)b*R*C;
  u16* ob = out + (size_t)b*R*C;
  #pragma unroll
  for (int k = 0; k < 4; ++k) tile[ty+k*8][tx] = f2bf(ib[(size_t)(r0+ty+k*8)*C + c0+tx]);
  __syncthreads();
  #pragma unroll
  for (int k = 0; k < 4; ++k) ob[(size_t)(c0+ty+k*8)*R + r0+tx] = tile[tx][ty+k*8];
}

// 4 fused 1024x1024 f32->bf16 transposes (z picks matrix)
__global__ __launch_bounds__(256) void k_trf4(
    const float* __restrict__ A0, const float* __restrict__ A1,
    const float* __restrict__ A2, const float* __restrict__ A3,
    u16* __restrict__ O0, u16* __restrict__ O1, u16* __restrict__ O2, u16* __restrict__ O3){
  __shared__ u16 tile[32][34];
  int z = blockIdx.z;
  const float* in = (z==0)?A0:(z==1)?A1:(z==2)?A2:A3;
  u16* out = (z==0)?O0:(z==1)?O1:(z==2)?O2:O3;
  int c0 = blockIdx.x*32, r0 = blockIdx.y*32;
  int tx = threadIdx.x & 31, ty = threadIdx.x >> 5;
  #pragma unroll
  for (int k = 0; k < 4; ++k) tile[ty+k*8][tx] = f2bf(in[(size_t)(r0+ty+k*8)*1024 + c0+tx]);
  __syncthreads();
  #pragma unroll
  for (int k = 0; k < 4; ++k) out[(size_t)(c0+ty+k*8)*1024 + r0+tx] = tile[tx][ty+k*8];
}

__global__ __launch_bounds__(256) void k_cast(const float* __restrict__ in, u16* __restrict__ out, int n){
  int i = blockIdx.x*256 + threadIdx.x;
  if (i < n) out[i] = f2bf(in[i]);
}

// ---------------- MFMA GEMM body: M=2048,N=1024,K=1024, A[M][K] bf16, BT[N][K] bf16 ----------------
// 64x64 tile, 4 waves. mode 0: C f32 [M][N]; mode 1: C bf16 chunked [h][c][tok][d]
__device__ __forceinline__ void gemm_body(const u16* __restrict__ A, const u16* __restrict__ BT,
    void* __restrict__ Cp, int mode){
  __shared__ char As[8192];
  __shared__ char Bs[8192];
  int t = threadIdx.x; int l = t & 63, w = t >> 6, lr16 = l & 15, lg = l >> 4;
  int bm = blockIdx.x*64, bn = blockIdx.y*64;
  f32x4 acc[4];
  #pragma unroll
  for (int mt = 0; mt < 4; ++mt) acc[mt] = (f32x4){0.f,0.f,0.f,0.f};
  for (int k0 = 0; k0 < 1024; k0 += 64){
    #pragma unroll
    for (int i = 0; i < 2; ++i){ int e = (i*256+t)*8; int row = e>>6, col = e&63;
      *(s16x8*)(As + row*128 + swzb(row, col*2)) = *(const s16x8*)(A + (size_t)(bm+row)*1024 + k0 + col);
      *(s16x8*)(Bs + row*128 + swzb(row, col*2)) = *(const s16x8*)(BT + (size_t)(bn+row)*1024 + k0 + col); }
    __syncthreads();
    #pragma unroll
    for (int ks = 0; ks < 2; ++ks){
      int rowb = w*16 + lr16;
      s16x8 y = *(const s16x8*)(Bs + rowb*128 + swzb(rowb, (ks*32+lg*8)*2));
      #pragma unroll
      for (int mt = 0; mt < 4; ++mt){ int row = mt*16 + lr16;
        s16x8 xa = *(const s16x8*)(As + row*128 + swzb(row, (ks*32+lg*8)*2));
        acc[mt] = MFMA(xa, y, acc[mt]); }
    }
    __syncthreads();
  }
  #pragma unroll
  for (int mt = 0; mt < 4; ++mt)
    #pragma unroll
    for (int j = 0; j < 4; ++j){
      int row = bm + mt*16 + lg*4 + j;
      int coln = bn + w*16 + lr16;
      if (mode == 0) ((float*)Cp)[(size_t)row*1024 + coln] = acc[mt][j];
      else { int cI = row>>6, tok = row&63, h = coln>>7, d = coln&127;
        ((u16*)Cp)[((size_t)(h*32+cI)*64 + tok)*128 + d] = f2bf(acc[mt][j]); }
    }
}

__global__ __launch_bounds__(256) void k_gemm_bf(const u16* __restrict__ A, const u16* __restrict__ BT,
    void* __restrict__ Cp, int mode){ gemm_body(A, BT, Cp, mode); }

// fused QKV: z=0 K, z=1 V, z=2 Q
__global__ __launch_bounds__(256) void k_gemm3(
    const u16* __restrict__ s_bf, const u16* __restrict__ r_bf,
    const u16* __restrict__ WkT, const u16* __restrict__ WvT, const u16* __restrict__ WqT,
    u16* __restrict__ Kc, u16* __restrict__ Vc, u16* __restrict__ Qc){
  int z = blockIdx.z;
  const u16* A = (z==2) ? r_bf : s_bf;
  const u16* BT = (z==0) ? WkT : (z==1) ? WvT : WqT;
  u16* C = (z==0) ? Kc : (z==1) ? Vc : Qc;
  gemm_body(A, BT, (void*)C, 1);
}

// ---------------- fused gradient (1024 threads = 16 waves) ----------------
// LDS (160KB): a[64][512] swza (->duT[512][64] swzb) | upT[512][64] swzb (->kcT[128][64] swzb)
//            | dh[64][128] swzb rows 256B (scr first 4KB) | dhT[128][64] swzb
__global__ __launch_bounds__(1024) void k_grad(
    const u16* __restrict__ Kc, const u16* __restrict__ Vc, const float* __restrict__ lrc,
    const u16* __restrict__ w0T, const u16* __restrict__ w1T, const u16* __restrict__ w1bf,
    const float* __restrict__ mg,
    u16* __restrict__ SW0, u16* __restrict__ SW1, float* __restrict__ SG){
  extern __shared__ char sm[];
  char* a_s   = sm;            // 64KB
  char* upT_s = sm + 65536;    // 64KB
  char* dh_s  = sm + 131072;   // 16KB
  char* dhT_s = sm + 147456;   // 16KB
  char* duT_s = a_s;           // alias after B1
  char* kcT_s = upT_s;         // alias after B2
  float* scr  = (float*)dh_s;  // ssq[0..255], dot[256..511], dga[512..1023]

  int c = blockIdx.x, bh = blockIdx.y, t = threadIdx.x;
  size_t bc = (size_t)bh*NCH + c;
  int l = t & 63, w = t >> 6, lr16 = l & 15, lg = l >> 4;
  int tg = w & 3, dq = w >> 2;       // token group 0..3, quarter 0..3
  int tokb = tg*16, tok0 = tokb + lg*4;

  const u16* kc_g = Kc + bc*8192;
  const u16* vc_g = Vc + bc*8192;

  // ---- P2: u = kc @ w0 ; a = gelu(u) -> a_s ; gelu'(u) -> upT_s ----
  s16x8 xk[4];
  #pragma unroll
  for (int k = 0; k < 4; ++k)
    xk[k] = *(const s16x8*)(kc_g + (size_t)(tokb+lr16)*128 + k*32 + lg*8);
  const u16* w0Th = w0T + (size_t)bh*65536;
  #pragma unroll
  for (int n0h = 0; n0h < 8; ++n0h){
    int n0 = dq*8 + n0h;
    f32x4 acc = {0.f,0.f,0.f,0.f};
    const u16* yb = w0Th + (size_t)(n0*16 + lr16)*128 + lg*8;
    #pragma unroll
    for (int k = 0; k < 4; ++k) acc = MFMA(xk[k], *(const s16x8*)(yb + k*32), acc);
    int hid = n0*16 + lr16;
    float upv[4];
    #pragma unroll
    for (int j = 0; j < 4; ++j){
      int tok = tok0 + j;
      float u = acc[j];
      float cdf = 0.5f*(1.f + erff(u*0.70710678118654752f));
      upv[j] = cdf + u*0.3989422804014327f*expf(-0.5f*u*u);
      *(u16*)(a_s + tok*1024 + swza(tok, hid*2)) = f2bf(u*cdf);
    }
    *(uint2*)(upT_s + hid*128 + swzb(hid, tok0*2)) =
        make_uint2(pack2(upv[0], upv[1]), pack2(upv[2], upv[3]));
  }
  __syncthreads();

  // ---- P3: h = a @ w1 (toks tg, d range dq*32..+31), rmsnorm fwd+bwd ----
  s16x8 xa[16];
  #pragma unroll
  for (int k = 0; k < 16; ++k){ int row = tokb + lr16;
    xa[k] = *(const s16x8*)(a_s + row*1024 + swza(row, (k*32+lg*8)*2)); }
  const u16* w1Th = w1T + (size_t)bh*65536;
  f32x4 hD[2];
  #pragma unroll
  for (int n0l = 0; n0l < 2; ++n0l){
    int d = dq*32 + n0l*16 + lr16;
    f32x4 acc = {0.f,0.f,0.f,0.f};
    const u16* yb = w1Th + (size_t)d*512 + lg*8;
    #pragma unroll
    for (int k = 0; k < 16; ++k) acc = MFMA(xa[k], *(const s16x8*)(yb + k*32), acc);
    hD[n0l] = acc;
  }
  #pragma unroll
  for (int j = 0; j < 4; ++j){
    float s = hD[0][j]*hD[0][j] + hD[1][j]*hD[1][j];
    s += __shfl_xor(s,1); s += __shfl_xor(s,2); s += __shfl_xor(s,4); s += __shfl_xor(s,8);
    if (lr16 == 0) scr[dq*64 + tok0 + j] = s;
  }
  __syncthreads();
  float rv[4], lrv[4], dotp[4];
  #pragma unroll
  for (int j = 0; j < 4; ++j){
    int tok = tok0 + j;
    float tot = scr[tok] + scr[64+tok] + scr[128+tok] + scr[192+tok];
    rv[j] = rsqrtf(tot*(1.f/128.f) + 1e-6f);
    lrv[j] = lrc[bc*64 + tok];
    dotp[j] = 0.f;
  }
  float dn[2][4];
  #pragma unroll
  for (int n0l = 0; n0l < 2; ++n0l){
    int d = dq*32 + n0l*16 + lr16;
    float g0 = mg[(size_t)bh*128 + d];
    float dgav = 0.f;
    #pragma unroll
    for (int j = 0; j < 4; ++j){
      int tok = tok0 + j;
      float h = hD[n0l][j];
      float nrm = h*rv[j];
      float kcv = bf2f(kc_g[(size_t)tok*128 + d]);
      float vcv = bf2f(vc_g[(size_t)tok*128 + d]);
      float p = nrm*g0 + kcv;
      float dp = (2.f/128.f)*lrv[j]*(p - vcv);
      dgav += dp*nrm;
      float dnv = dp*g0;
      dn[n0l][j] = dnv;
      dotp[j] += dnv*h;
    }
    dgav += __shfl_xor(dgav,16); dgav += __shfl_xor(dgav,32);
    if (lg == 0) scr[512 + tg*128 + d] = dgav;
  }
  #pragma unroll
  for (int j = 0; j < 4; ++j){
    float dd = dotp[j];
    dd += __shfl_xor(dd,1); dd += __shfl_xor(dd,2); dd += __shfl_xor(dd,4); dd += __shfl_xor(dd,8);
    if (lr16 == 0) scr[256 + dq*64 + tok0 + j] = dd;
  }
  __syncthreads();
  float dotv[4];
  #pragma unroll
  for (int j = 0; j < 4; ++j){
    int tok = tok0 + j;
    dotv[j] = scr[256+tok] + scr[256+64+tok] + scr[256+128+tok] + scr[256+192+tok];
  }
  if (t < 128){
    float s = scr[512+t] + scr[512+128+t] + scr[512+256+t] + scr[512+384+t];
    SG[bc*128 + t] = -s;
  }
  __syncthreads();   // scratch fully consumed; dh region now writable
  #pragma unroll
  for (int n0l = 0; n0l < 2; ++n0l){
    int d = dq*32 + n0l*16 + lr16;
    float dhv[4];
    #pragma unroll
    for (int j = 0; j < 4; ++j){
      int tok = tok0 + j;
      float c3 = rv[j]*rv[j]*rv[j]*(1.f/128.f);
      dhv[j] = rv[j]*dn[n0l][j] - c3*dotv[j]*hD[n0l][j];
      *(u16*)(dh_s + tok*256 + swzb(tok, d*2)) = f2bf(dhv[j]);
    }
    *(uint2*)(dhT_s + d*128 + swzb(d, tok0*2)) =
        make_uint2(pack2(dhv[0], dhv[1]), pack2(dhv[2], dhv[3]));
  }
  __syncthreads();

  // ---- B1: SW1[128 d][512 hid] = -(dh^T @ a). waves: mh = w&1 (d-half), nh = w>>1 (64 hid) ----
  {
    int mh = w & 1, nh = w >> 1;
    s16x8 xD[4][2];
    #pragma unroll
    for (int mt = 0; mt < 4; ++mt){ int row = mh*64 + mt*16 + lr16;
      #pragma unroll
      for (int ks = 0; ks < 2; ++ks)
        xD[mt][ks] = *(const s16x8*)(dhT_s + row*128 + swzb(row, (ks*32+lg*8)*2)); }
    s16x8 yB[4][2];
    #pragma unroll
    for (int n0l = 0; n0l < 4; ++n0l){
      int hid = nh*64 + n0l*16 + lr16;
      #pragma unroll
      for (int ks = 0; ks < 2; ++ks){
        s16x8 v;
        #pragma unroll
        for (int e = 0; e < 8; ++e){ int tok = ks*32 + lg*8 + e;
          v[e] = *(const short*)(a_s + tok*1024 + swza(tok, hid*2)); }
        yB[n0l][ks] = v;
      }
    }
    #pragma unroll 2
    for (int mt = 0; mt < 4; ++mt){
      #pragma unroll
      for (int n0l = 0; n0l < 4; ++n0l){
        f32x4 acc = {0.f,0.f,0.f,0.f};
        acc = MFMA(xD[mt][0], yB[n0l][0], acc);
        acc = MFMA(xD[mt][1], yB[n0l][1], acc);
        int hid = nh*64 + n0l*16 + lr16;
        #pragma unroll
        for (int j = 0; j < 4; ++j)
          SW1[bc*65536 + (size_t)(mh*64 + mt*16 + lg*4 + j)*512 + hid] = f2bf(-acc[j]);
      }
    }
  }
  __syncthreads();   // a_s dead -> duT

  // ---- B2: duT[512 hid][64 tok] = (dh @ w1^T) * up.  wave: 32 hid (n0l 0..1) ----
  {
    s16x8 xDh[4][4];
    #pragma unroll
    for (int mt = 0; mt < 4; ++mt){ int row = mt*16 + lr16;
      #pragma unroll
      for (int ks = 0; ks < 4; ++ks)
        xDh[mt][ks] = *(const s16x8*)(dh_s + row*256 + swzb(row, (ks*32+lg*8)*2)); }
    const u16* w1b = w1bf + (size_t)bh*65536;
    #pragma unroll
    for (int n0l = 0; n0l < 2; ++n0l){
      int hid = w*32 + n0l*16 + lr16;
      s16x8 yW[4];
      #pragma unroll
      for (int ks = 0; ks < 4; ++ks)
        yW[ks] = *(const s16x8*)(w1b + (size_t)hid*128 + ks*32 + lg*8);
      #pragma unroll
      for (int mt = 0; mt < 4; ++mt){
        f32x4 acc = {0.f,0.f,0.f,0.f};
        #pragma unroll
        for (int ks = 0; ks < 4; ++ks) acc = MFMA(xDh[mt][ks], yW[ks], acc);
        int tk0 = mt*16 + lg*4;
        uint2 ur = *(const uint2*)(upT_s + hid*128 + swzb(hid, tk0*2));
        float u0 = bf2f((u16)(ur.x & 0xffff)), u1 = bf2f((u16)(ur.x >> 16));
        float u2 = bf2f((u16)(ur.y & 0xffff)), u3 = bf2f((u16)(ur.y >> 16));
        *(uint2*)(duT_s + hid*128 + swzb(hid, tk0*2)) =
            make_uint2(pack2(acc[0]*u0, acc[1]*u1), pack2(acc[2]*u2, acc[3]*u3));
      }
    }
  }
  __syncthreads();   // upT dead -> kcT

  // ---- build kcT[128 d][64 tok] from global kc (1024 threads, one pass) ----
  {
    int tok = t & 63, d0 = (t >> 6)*8;
    s16x8 kv = *(const s16x8*)(kc_g + (size_t)tok*128 + d0);
    #pragma unroll
    for (int e = 0; e < 8; ++e)
      *(u16*)(kcT_s + (d0+e)*128 + swzb(d0+e, tok*2)) = kv[e];
  }
  __syncthreads();

  // ---- B3: SW0[512 hid][128 d] = -(duT @ kc). waves: mseg = w&7 (64 hid), nh2 = w>>3 (d-half) ----
  {
    int mseg = w & 7, nh2 = w >> 3;
    s16x8 xU[4][2];
    #pragma unroll
    for (int mi = 0; mi < 4; ++mi){ int hid = mseg*64 + mi*16 + lr16;
      #pragma unroll
      for (int ks = 0; ks < 2; ++ks)
        xU[mi][ks] = *(const s16x8*)(duT_s + hid*128 + swzb(hid, (ks*32+lg*8)*2)); }
    #pragma unroll 2
    for (int n0 = 0; n0 < 4; ++n0){
      int d = nh2*64 + n0*16 + lr16;
      s16x8 yK[2];
      #pragma unroll
      for (int ks = 0; ks < 2; ++ks)
        yK[ks] = *(const s16x8*)(kcT_s + d*128 + swzb(d, (ks*32+lg*8)*2));
      #pragma unroll
      for (int mi = 0; mi < 4; ++mi){
        f32x4 acc = {0.f,0.f,0.f,0.f};
        acc = MFMA(xU[mi][0], yK[0], acc);
        acc = MFMA(xU[mi][1], yK[1], acc);
        #pragma unroll
        for (int j = 0; j < 4; ++j)
          SW0[bc*65536 + (size_t)(mseg*64 + mi*16 + lg*4 + j)*128 + d] = f2bf(-acc[j]);
      }
    }
  }
}

// ---------------- scans (f32 state, bf16 storage) ----------------
__global__ __launch_bounds__(256) void k_scan(
    const u16* __restrict__ w0T, const u16* __restrict__ w1T, const float* __restrict__ mg,
    const u16* __restrict__ SW0, const u16* __restrict__ SW1, const float* __restrict__ SG,
    const float* __restrict__ momb, const float* __restrict__ decb,
    u16* __restrict__ W0C, u16* __restrict__ W1C, float* __restrict__ GC){
  int bh = blockIdx.y;
  int e = blockIdx.x*256 + threadIdx.x;
  const float* momp = momb + bh*NCH;
  const float* decp = decb + bh*NCH;
  float m = 0.f, Wv;
  if (e < 65536){
    Wv = bf2f(w0T[(size_t)bh*65536 + e]);
    const u16* su = SW0 + (size_t)bh*NCH*65536 + e;
    u16* outp = W0C + (size_t)bh*NCH*65536 + e;
    for (int c = 0; c < NCH; ++c){
      outp[(size_t)c*65536] = f2bf(Wv);
      m = momp[c]*m + bf2f(su[(size_t)c*65536]);
      Wv = (1.f - decp[c])*Wv + m;
    }
  } else if (e < 131072){
    int e2 = e - 65536;
    Wv = bf2f(w1T[(size_t)bh*65536 + e2]);
    const u16* su = SW1 + (size_t)bh*NCH*65536 + e2;
    u16* outp = W1C + (size_t)bh*NCH*65536 + e2;
    for (int c = 0; c < NCH; ++c){
      outp[(size_t)c*65536] = f2bf(Wv);
      m = momp[c]*m + bf2f(su[(size_t)c*65536]);
      Wv = (1.f - decp[c])*Wv + m;
    }
  } else if (e < 131200){
    int e3 = e - 131072;
    Wv = mg[(size_t)bh*128 + e3];
    const float* su = SG + (size_t)bh*NCH*128 + e3;
    float* outp = GC + (size_t)bh*NCH*128 + e3;
    for (int c = 0; c < NCH; ++c){
      outp[(size_t)c*128] = Wv;
      m = momp[c]*m + su[(size_t)c*128];
      Wv = (1.f - decp[c])*Wv + m;
    }
  }
}

// ---------------- retrieval (1024 threads = 16 waves) ----------------
__global__ __launch_bounds__(1024) void k_retr(
    const u16* __restrict__ Qc, const u16* __restrict__ W0C, const u16* __restrict__ W1C,
    const float* __restrict__ GC, const float* __restrict__ gate, u16* __restrict__ OH){
  extern __shared__ char sm[];
  char* a_s = sm;                      // [64][512] swza
  float* scr = (float*)(sm + 65536);   // [256]
  int c = blockIdx.x, bh = blockIdx.y, t = threadIdx.x;
  size_t bc = (size_t)bh*NCH + c;
  int l = t & 63, w = t >> 6, lr16 = l & 15, lg = l >> 4;
  int tg = w & 3, dq = w >> 2;
  int tokb = tg*16, tok0 = tokb + lg*4;
  const u16* q_g = Qc + bc*8192;

  s16x8 xq[4];
  #pragma unroll
  for (int k = 0; k < 4; ++k)
    xq[k] = *(const s16x8*)(q_g + (size_t)(tokb+lr16)*128 + k*32 + lg*8);
  const u16* w0c = W0C + bc*65536;
  #pragma unroll
  for (int n0h = 0; n0h < 8; ++n0h){
    int n0 = dq*8 + n0h;
    f32x4 acc = {0.f,0.f,0.f,0.f};
    const u16* yb = w0c + (size_t)(n0*16 + lr16)*128 + lg*8;
    #pragma unroll
    for (int k = 0; k < 4; ++k) acc = MFMA(xq[k], *(const s16x8*)(yb + k*32), acc);
    int hid = n0*16 + lr16;
    #pragma unroll
    for (int j = 0; j < 4; ++j){
      int tok = tok0 + j;
      float u = acc[j];
      float av = u*0.5f*(1.f + erff(u*0.70710678118654752f));
      *(u16*)(a_s + tok*1024 + swza(tok, hid*2)) = f2bf(av);
    }
  }
  __syncthreads();
  s16x8 xa[16];
  #pragma unroll
  for (int k = 0; k < 16; ++k){ int row = tokb + lr16;
    xa[k] = *(const s16x8*)(a_s + row*1024 + swza(row, (k*32+lg*8)*2)); }
  const u16* w1c = W1C + bc*65536;
  f32x4 hD[2];
  #pragma unroll
  for (int n0l = 0; n0l < 2; ++n0l){
    int d = dq*32 + n0l*16 + lr16;
    f32x4 acc = {0.f,0.f,0.f,0.f};
    const u16* yb = w1c + (size_t)d*512 + lg*8;
    #pragma unroll
    for (int k = 0; k < 16; ++k) acc = MFMA(xa[k], *(const s16x8*)(yb + k*32), acc);
    hD[n0l] = acc;
  }
  #pragma unroll
  for (int j = 0; j < 4; ++j){
    float s = hD[0][j]*hD[0][j] + hD[1][j]*hD[1][j];
    s += __shfl_xor(s,1); s += __shfl_xor(s,2); s += __shfl_xor(s,4); s += __shfl_xor(s,8);
    if (lr16 == 0) scr[dq*64 + tok0 + j] = s;
  }
  __syncthreads();
  float rv[4], gtv[4];
  #pragma unroll
  for (int j = 0; j < 4; ++j){
    int tok = tok0 + j;
    float tot = scr[tok] + scr[64+tok] + scr[128+tok] + scr[192+tok];
    rv[j] = rsqrtf(tot*(1.f/128.f) + 1e-6f);
    gtv[j] = gate[(size_t)(c*64 + tok)*8 + bh];
  }
  #pragma unroll
  for (int n0l = 0; n0l < 2; ++n0l){
    int d = dq*32 + n0l*16 + lr16;
    float g0 = GC[bc*128 + d];
    #pragma unroll
    for (int j = 0; j < 4; ++j){
      int tok = tok0 + j; int tokg = c*64 + tok;
      float qv = bf2f(q_g[(size_t)tok*128 + d]);
      float p = hD[n0l][j]*rv[j]*g0 + qv;
      OH[(size_t)tokg*1024 + bh*128 + d] = f2bf(p*gtv[j]);
    }
  }
}

// ---------------- launch ----------------
extern "C" void kernel_launch(void* const* d_in, const int* in_sizes, int n_in,
                              void* d_out, int out_size, void* d_ws, size_t ws_size,
                              hipStream_t stream) {
  (void)in_sizes; (void)n_in; (void)out_size; (void)ws_size;
  const float* x     = (const float*)d_in[0];
  const float* snw   = (const float*)d_in[1];
  const float* rnw   = (const float*)d_in[2];
  const float* Wq    = (const float*)d_in[3];
  const float* Wk    = (const float*)d_in[4];
  const float* Wv    = (const float*)d_in[5];
  const float* Wstep = (const float*)d_in[6];
  const float* bstep = (const float*)d_in[7];
  const float* Wmom  = (const float*)d_in[8];
  const float* bmom  = (const float*)d_in[9];
  const float* Wdec  = (const float*)d_in[10];
  const float* bdec  = (const float*)d_in[11];
  const float* gateW = (const float*)d_in[12];
  const float* combW = (const float*)d_in[13];
  const float* mw0   = (const float*)d_in[14];
  const float* mw1   = (const float*)d_in[15];
  const float* mg    = (const float*)d_in[16];
  float* out = (float*)d_out;

  char* Wb = (char*)d_ws;
  u16* Qc    = (u16*)(Wb + 0*MB);
  u16* Kc    = (u16*)(Wb + 4*MB);
  u16* Vc    = (u16*)(Wb + 8*MB);
  u16* s_bf  = (u16*)(Wb + 12*MB);
  u16* r_bf  = (u16*)(Wb + 16*MB);
  u16* WqT   = (u16*)(Wb + 20*MB);
  u16* WkT   = (u16*)(Wb + 22*MB);
  u16* WvT   = (u16*)(Wb + 24*MB);
  u16* combT = (u16*)(Wb + 26*MB);
  u16* w0T   = (u16*)(Wb + 28*MB);
  u16* w1T   = (u16*)(Wb + 29*MB);
  u16* w1bf  = (u16*)(Wb + 30*MB);
  u16* OH    = (u16*)(Wb + 31*MB);
  u16* SW0   = (u16*)(Wb + 35*MB);
  u16* SW1   = (u16*)(Wb + 67*MB);
  u16* W0C   = (u16*)(Wb + 99*MB);
  u16* W1C   = (u16*)(Wb + 131*MB);
  float* pooled = (float*)(Wb + 163*MB);
  float* lrc    = (float*)(Wb + 163*MB + 131072);
  float* momb   = (float*)(Wb + 163*MB + 196608);
  float* decb   = (float*)(Wb + 163*MB + 197632);
  float* gate   = (float*)(Wb + 163*MB + 198656);
  float* SG     = (float*)(Wb + 163*MB + 264192);
  float* GC     = (float*)(Wb + 163*MB + 395264);

  hipFuncSetAttribute((const void*)k_grad, hipFuncAttributeMaxDynamicSharedMemorySize, 163840);
  hipFuncSetAttribute((const void*)k_retr, hipFuncAttributeMaxDynamicSharedMemorySize, 66560);

  k_rmsnorm<<<2048, 256, 0, stream>>>(x, snw, rnw, s_bf, r_bf);
  k_pool<<<dim3(32,4), 256, 0, stream>>>(s_bf, pooled);
  k_lrgate<<<512, 256, 0, stream>>>(s_bf, r_bf, Wstep, bstep, gateW, lrc, gate);
  k_momdec<<<32, 64, 0, stream>>>(pooled, Wmom, bmom, Wdec, bdec, momb, decb);
  k_trf4<<<dim3(32,32,4), 256, 0, stream>>>(Wq, Wk, Wv, combW, WqT, WkT, WvT, combT);
  k_trf<<<dim3(16,4,8), 256, 0, stream>>>(mw0, w0T, 128, 512);
  k_trf<<<dim3(4,16,8), 256, 0, stream>>>(mw1, w1T, 512, 128);
  k_cast<<<2048, 256, 0, stream>>>(mw1, w1bf, 524288);
  k_gemm3<<<dim3(32,16,3), 256, 0, stream>>>(s_bf, r_bf, WkT, WvT, WqT, Kc, Vc, Qc);
  k_grad<<<dim3(32,8), 1024, 163840, stream>>>(Kc, Vc, lrc, w0T, w1T, w1bf, mg, SW0, SW1, SG);
  k_scan<<<dim3(513,8), 256, 0, stream>>>(w0T, w1T, mg, SW0, SW1, SG, momb, decb, W0C, W1C, GC);
  k_retr<<<dim3(32,8), 1024, 66560, stream>>>(Qc, W0C, W1C, GC, gate, OH);
  k_gemm_bf<<<dim3(32,16), 256, 0, stream>>>(OH, combT, (void*)out, 0);
}

// Round 6
// 320.077 us; speedup vs baseline: 1.3568x; 1.3568x over previous
//
#include <hip/hip_runtime.h>
#include <hip/hip_bf16.h>
#include <math.h>

#define NH   8
#define DHD  128
#define HIDN 512
#define CHK  64
#define NCH  32
#define MB   1048576ull

typedef unsigned short u16;
typedef unsigned int   u32;
typedef short s16x8 __attribute__((ext_vector_type(8)));
typedef float f32x4 __attribute__((ext_vector_type(4)));

#define MFMA(a,b,c) __builtin_amdgcn_mfma_f32_16x16x32_bf16((a),(b),(c),0,0,0)

__device__ __forceinline__ float bf2f(u16 v){ return __uint_as_float(((u32)v) << 16); }
__device__ __forceinline__ u16 f2bf(float f){
  u32 u = __float_as_uint(f);
  u += 0x7fffu + ((u >> 16) & 1u);
  return (u16)(u >> 16);
}
__device__ __forceinline__ u32 pack2(float a, float b){
  return (u32)f2bf(a) | ((u32)f2bf(b) << 16);
}
__device__ __forceinline__ float waveRedSum(float v){
  #pragma unroll
  for (int off = 32; off; off >>= 1) v += __shfl_xor(v, off);
  return v;
}
// swizzles
__device__ __forceinline__ int swzb(int row, int colb){ return colb ^ ((row & 7) << 4); }   // 256B+ rows
__device__ __forceinline__ int swz64(int row, int colb){ return colb ^ ((row & 3) << 4); }  // 64B rows
// [*][1024B] a-tile: extra spread of row bits 3,4 into byte bits 5,6 (column-gather friendly)
__device__ __forceinline__ int swza(int row, int colb){
  return colb ^ ((row & 7) << 4) ^ (((row >> 3) & 3) << 5);
}

// ---------------- prep ----------------

__global__ __launch_bounds__(256) void k_rmsnorm(const float* __restrict__ x,
    const float* __restrict__ wst, const float* __restrict__ wrt,
    u16* __restrict__ s_bf, u16* __restrict__ r_bf){
  int row = blockIdx.x, t = threadIdx.x;
  float4 v = ((const float4*)(x + (size_t)row*1024))[t];
  float ss = v.x*v.x + v.y*v.y + v.z*v.z + v.w*v.w;
  ss = waveRedSum(ss);
  __shared__ float red[4];
  int wv = t >> 6, ln = t & 63;
  if (ln == 0) red[wv] = ss;
  __syncthreads();
  float rr = rsqrtf((red[0]+red[1]+red[2]+red[3])*(1.f/1024.f) + 1e-6f);
  float4 a = ((const float4*)wst)[t];
  float4 b = ((const float4*)wrt)[t];
  uint2 so = make_uint2(pack2(v.x*rr*a.x, v.y*rr*a.y), pack2(v.z*rr*a.z, v.w*rr*a.w));
  uint2 ro = make_uint2(pack2(v.x*rr*b.x, v.y*rr*b.y), pack2(v.z*rr*b.z, v.w*rr*b.w));
  *(uint2*)(s_bf + (size_t)row*1024 + t*4) = so;
  *(uint2*)(r_bf + (size_t)row*1024 + t*4) = ro;
}

__global__ __launch_bounds__(256) void k_pool(const u16* __restrict__ s_bf, float* __restrict__ pooled){
  int c = blockIdx.x; int d = blockIdx.y*256 + threadIdx.x;
  float acc = 0.f;
  for (int tt = 0; tt < 64; ++tt) acc += bf2f(s_bf[((size_t)c*64+tt)*1024 + d]);
  pooled[(size_t)c*1024 + d] = acc * (1.f/64.f);
}

__global__ __launch_bounds__(256) void k_lrgate(const u16* __restrict__ s_bf, const u16* __restrict__ r_bf,
    const float* __restrict__ Wstep, const float* __restrict__ bstep,
    const float* __restrict__ gateW,
    float* __restrict__ lrc, float* __restrict__ gate){
  int wv = threadIdx.x >> 6, ln = threadIdx.x & 63;
  int tok = blockIdx.x*4 + wv;
  const u16* srow = s_bf + (size_t)tok*1024;
  const u16* rrow = r_bf + (size_t)tok*1024;
  for (int o = 0; o < 16; ++o){
    int h = o & 7;
    const u16* src = (o < 8) ? srow : rrow;
    const float* W = (o < 8) ? Wstep : gateW;
    float acc = 0.f;
    for (int k = ln; k < 1024; k += 64) acc += bf2f(src[k])*W[(size_t)k*8+h];
    acc = waveRedSum(acc);
    if (ln == 0){
      if (o < 8){
        float v = 1.f/(1.f+expf(-(acc + bstep[h])));
        lrc[((size_t)h*NCH + (tok>>6))*CHK + (tok&63)] = v;
      } else {
        gate[(size_t)tok*8 + h] = 1.f/(1.f+expf(-acc));
      }
    }
  }
}

__global__ __launch_bounds__(64) void k_momdec(const float* __restrict__ pooled,
    const float* __restrict__ Wmom, const float* __restrict__ bmom,
    const float* __restrict__ Wdec, const float* __restrict__ bdec,
    float* __restrict__ momb, float* __restrict__ decb){
  int c = blockIdx.x, ln = threadIdx.x;
  const float* prow = pooled + (size_t)c*1024;
  for (int o = 0; o < 16; ++o){
    int h = o & 7;
    const float* W = (o < 8) ? Wmom : Wdec;
    float acc = 0.f;
    for (int k = ln; k < 1024; k += 64) acc += prow[k]*W[(size_t)k*8+h];
    acc = waveRedSum(acc);
    if (ln == 0){
      float bb = (o < 8) ? bmom[h] : bdec[h];
      float v = 1.f/(1.f+expf(-(acc+bb)));
      if (o < 8) momb[h*NCH + c] = v; else decb[h*NCH + c] = v;
    }
  }
}

// batched transpose f32 -> bf16 : in (b,R,C) -> out (b,C,R)
__global__ __launch_bounds__(256) void k_trf(const float* __restrict__ in, u16* __restrict__ out, int R, int C){
  __shared__ u16 tile[32][34];
  int b = blockIdx.z; int c0 = blockIdx.x*32, r0 = blockIdx.y*32;
  int tx = threadIdx.x & 31, ty = threadIdx.x >> 5;
  const float* ib = in + (size_t)b*R*C;
  u16* ob = out + (size_t)b*R*C;
  #pragma unroll
  for (int k = 0; k < 4; ++k) tile[ty+k*8][tx] = f2bf(ib[(size_t)(r0+ty+k*8)*C + c0+tx]);
  __syncthreads();
  #pragma unroll
  for (int k = 0; k < 4; ++k) ob[(size_t)(c0+ty+k*8)*R + r0+tx] = tile[tx][ty+k*8];
}

// 4 fused 1024x1024 f32->bf16 transposes (z picks matrix)
__global__ __launch_bounds__(256) void k_trf4(
    const float* __restrict__ A0, const float* __restrict__ A1,
    const float* __restrict__ A2, const float* __restrict__ A3,
    u16* __restrict__ O0, u16* __restrict__ O1, u16* __restrict__ O2, u16* __restrict__ O3){
  __shared__ u16 tile[32][34];
  int z = blockIdx.z;
  const float* in = (z==0)?A0:(z==1)?A1:(z==2)?A2:A3;
  u16* out = (z==0)?O0:(z==1)?O1:(z==2)?O2:O3;
  int c0 = blockIdx.x*32, r0 = blockIdx.y*32;
  int tx = threadIdx.x & 31, ty = threadIdx.x >> 5;
  #pragma unroll
  for (int k = 0; k < 4; ++k) tile[ty+k*8][tx] = f2bf(in[(size_t)(r0+ty+k*8)*1024 + c0+tx]);
  __syncthreads();
  #pragma unroll
  for (int k = 0; k < 4; ++k) out[(size_t)(c0+ty+k*8)*1024 + r0+tx] = tile[tx][ty+k*8];
}

__global__ __launch_bounds__(256) void k_cast(const float* __restrict__ in, u16* __restrict__ out, int n){
  int i = blockIdx.x*256 + threadIdx.x;
  if (i < n) out[i] = f2bf(in[i]);
}

// ---------------- MFMA GEMM body: M=2048,N=1024,K=1024 ----------------
__device__ __forceinline__ void gemm_body(const u16* __restrict__ A, const u16* __restrict__ BT,
    void* __restrict__ Cp, int mode){
  __shared__ char As[8192];
  __shared__ char Bs[8192];
  int t = threadIdx.x; int l = t & 63, w = t >> 6, lr16 = l & 15, lg = l >> 4;
  int bm = blockIdx.x*64, bn = blockIdx.y*64;
  f32x4 acc[4];
  #pragma unroll
  for (int mt = 0; mt < 4; ++mt) acc[mt] = (f32x4){0.f,0.f,0.f,0.f};
  for (int k0 = 0; k0 < 1024; k0 += 64){
    #pragma unroll
    for (int i = 0; i < 2; ++i){ int e = (i*256+t)*8; int row = e>>6, col = e&63;
      *(s16x8*)(As + row*128 + swzb(row, col*2)) = *(const s16x8*)(A + (size_t)(bm+row)*1024 + k0 + col);
      *(s16x8*)(Bs + row*128 + swzb(row, col*2)) = *(const s16x8*)(BT + (size_t)(bn+row)*1024 + k0 + col); }
    __syncthreads();
    #pragma unroll
    for (int ks = 0; ks < 2; ++ks){
      int rowb = w*16 + lr16;
      s16x8 y = *(const s16x8*)(Bs + rowb*128 + swzb(rowb, (ks*32+lg*8)*2));
      #pragma unroll
      for (int mt = 0; mt < 4; ++mt){ int row = mt*16 + lr16;
        s16x8 xa = *(const s16x8*)(As + row*128 + swzb(row, (ks*32+lg*8)*2));
        acc[mt] = MFMA(xa, y, acc[mt]); }
    }
    __syncthreads();
  }
  #pragma unroll
  for (int mt = 0; mt < 4; ++mt)
    #pragma unroll
    for (int j = 0; j < 4; ++j){
      int row = bm + mt*16 + lg*4 + j;
      int coln = bn + w*16 + lr16;
      if (mode == 0) ((float*)Cp)[(size_t)row*1024 + coln] = acc[mt][j];
      else { int cI = row>>6, tok = row&63, h = coln>>7, d = coln&127;
        ((u16*)Cp)[((size_t)(h*32+cI)*64 + tok)*128 + d] = f2bf(acc[mt][j]); }
    }
}

__global__ __launch_bounds__(256) void k_gemm_bf(const u16* __restrict__ A, const u16* __restrict__ BT,
    void* __restrict__ Cp, int mode){ gemm_body(A, BT, Cp, mode); }

__global__ __launch_bounds__(256) void k_gemm3(
    const u16* __restrict__ s_bf, const u16* __restrict__ r_bf,
    const u16* __restrict__ WkT, const u16* __restrict__ WvT, const u16* __restrict__ WqT,
    u16* __restrict__ Kc, u16* __restrict__ Vc, u16* __restrict__ Qc){
  int z = blockIdx.z;
  const u16* A = (z==2) ? r_bf : s_bf;
  const u16* BT = (z==0) ? WkT : (z==1) ? WvT : WqT;
  u16* C = (z==0) ? Kc : (z==1) ? Vc : Qc;
  gemm_body(A, BT, (void*)C, 1);
}

// ---------------- fused gradient, token-split: block = (chunk, token-half, head) ----------------
// 512 threads (8 waves), 80KB LDS -> 2 blocks/CU. Each block handles 32 tokens.
// Outer products (k=token) emit PARTIALS; k_scan sums the two halves.
// LDS: a[32][512] swza (->duT[512][32] swz64) | upT[512][32] swz64 (->kcT[128][32] swz64)
//    | dh[32][128] swzb rows 256B (scr first 2KB) | dhT[128][32] swz64
__global__ __launch_bounds__(512) void k_grad(
    const u16* __restrict__ Kc, const u16* __restrict__ Vc, const float* __restrict__ lrc,
    const u16* __restrict__ w0T, const u16* __restrict__ w1T, const u16* __restrict__ w1bf,
    const float* __restrict__ mg,
    u16* __restrict__ SW0p, u16* __restrict__ SW1p, float* __restrict__ SGp){
  extern __shared__ char sm[];
  char* a_s   = sm;            // 32KB
  char* upT_s = sm + 32768;    // 32KB
  char* dh_s  = sm + 65536;    // 8KB
  char* dhT_s = sm + 73728;    // 8KB
  char* duT_s = a_s;           // alias after B1
  char* kcT_s = upT_s;         // alias after B2
  float* scr  = (float*)dh_s;  // ssq[0..127], dot[128..255], dga[256..511]

  int bx = blockIdx.x;                 // 0..63
  int c = bx >> 1, th = bx & 1;
  int bh = blockIdx.y, t = threadIdx.x;
  size_t bc = (size_t)bh*NCH + c;
  int l = t & 63, w = t >> 6, lr16 = l & 15, lg = l >> 4;
  int tg = w & 1, hq = w >> 1;         // token tile (16), quarter
  int tokb = tg*16, tok0 = tokb + lg*4;

  const u16* kc_g = Kc + bc*8192 + th*4096;
  const u16* vc_g = Vc + bc*8192 + th*4096;

  // ---- P2: u = kc(32) @ w0 ; a = gelu(u) -> a_s ; gelu'(u) -> upT_s ----
  s16x8 xk[4];
  #pragma unroll
  for (int k = 0; k < 4; ++k)
    xk[k] = *(const s16x8*)(kc_g + (size_t)(tokb+lr16)*128 + k*32 + lg*8);
  const u16* w0Th = w0T + (size_t)bh*65536;
  #pragma unroll
  for (int n0h = 0; n0h < 8; ++n0h){
    int n0 = hq*8 + n0h;
    f32x4 acc = {0.f,0.f,0.f,0.f};
    const u16* yb = w0Th + (size_t)(n0*16 + lr16)*128 + lg*8;
    #pragma unroll
    for (int k = 0; k < 4; ++k) acc = MFMA(xk[k], *(const s16x8*)(yb + k*32), acc);
    int hid = n0*16 + lr16;
    float upv[4];
    #pragma unroll
    for (int j = 0; j < 4; ++j){
      int tok = tok0 + j;
      float u = acc[j];
      float cdf = 0.5f*(1.f + erff(u*0.70710678118654752f));
      upv[j] = cdf + u*0.3989422804014327f*expf(-0.5f*u*u);
      *(u16*)(a_s + tok*1024 + swza(tok, hid*2)) = f2bf(u*cdf);
    }
    *(uint2*)(upT_s + hid*64 + swz64(hid, tok0*2)) =
        make_uint2(pack2(upv[0], upv[1]), pack2(upv[2], upv[3]));
  }
  __syncthreads();

  // ---- P3: h = a @ w1 (32 toks, d range hq*32..+31), rmsnorm fwd+bwd ----
  s16x8 xa[16];
  #pragma unroll
  for (int k = 0; k < 16; ++k){ int row = tokb + lr16;
    xa[k] = *(const s16x8*)(a_s + row*1024 + swza(row, (k*32+lg*8)*2)); }
  const u16* w1Th = w1T + (size_t)bh*65536;
  f32x4 hD[2];
  #pragma unroll
  for (int n0l = 0; n0l < 2; ++n0l){
    int d = hq*32 + n0l*16 + lr16;
    f32x4 acc = {0.f,0.f,0.f,0.f};
    const u16* yb = w1Th + (size_t)d*512 + lg*8;
    #pragma unroll
    for (int k = 0; k < 16; ++k) acc = MFMA(xa[k], *(const s16x8*)(yb + k*32), acc);
    hD[n0l] = acc;
  }
  #pragma unroll
  for (int j = 0; j < 4; ++j){
    float s = hD[0][j]*hD[0][j] + hD[1][j]*hD[1][j];
    s += __shfl_xor(s,1); s += __shfl_xor(s,2); s += __shfl_xor(s,4); s += __shfl_xor(s,8);
    if (lr16 == 0) scr[hq*32 + tok0 + j] = s;
  }
  __syncthreads();
  float rv[4], lrv[4], dotp[4];
  #pragma unroll
  for (int j = 0; j < 4; ++j){
    int tok = tok0 + j;
    float tot = scr[tok] + scr[32+tok] + scr[64+tok] + scr[96+tok];
    rv[j] = rsqrtf(tot*(1.f/128.f) + 1e-6f);
    lrv[j] = lrc[bc*64 + th*32 + tok];
    dotp[j] = 0.f;
  }
  float dn[2][4];
  #pragma unroll
  for (int n0l = 0; n0l < 2; ++n0l){
    int d = hq*32 + n0l*16 + lr16;
    float g0 = mg[(size_t)bh*128 + d];
    float dgav = 0.f;
    #pragma unroll
    for (int j = 0; j < 4; ++j){
      int tok = tok0 + j;
      float h = hD[n0l][j];
      float nrm = h*rv[j];
      float kcv = bf2f(kc_g[(size_t)tok*128 + d]);
      float vcv = bf2f(vc_g[(size_t)tok*128 + d]);
      float p = nrm*g0 + kcv;
      float dp = (2.f/128.f)*lrv[j]*(p - vcv);
      dgav += dp*nrm;
      float dnv = dp*g0;
      dn[n0l][j] = dnv;
      dotp[j] += dnv*h;
    }
    dgav += __shfl_xor(dgav,16); dgav += __shfl_xor(dgav,32);
    if (lg == 0) scr[256 + tg*128 + d] = dgav;
  }
  #pragma unroll
  for (int j = 0; j < 4; ++j){
    float dd = dotp[j];
    dd += __shfl_xor(dd,1); dd += __shfl_xor(dd,2); dd += __shfl_xor(dd,4); dd += __shfl_xor(dd,8);
    if (lr16 == 0) scr[128 + hq*32 + tok0 + j] = dd;
  }
  __syncthreads();
  float dotv[4];
  #pragma unroll
  for (int j = 0; j < 4; ++j){
    int tok = tok0 + j;
    dotv[j] = scr[128+tok] + scr[160+tok] + scr[192+tok] + scr[224+tok];
  }
  if (t < 128)
    SGp[bc*256 + th*128 + t] = -(scr[256+t] + scr[384+t]);
  __syncthreads();   // scratch consumed; dh region writable
  #pragma unroll
  for (int n0l = 0; n0l < 2; ++n0l){
    int d = hq*32 + n0l*16 + lr16;
    float dhv[4];
    #pragma unroll
    for (int j = 0; j < 4; ++j){
      int tok = tok0 + j;
      float c3 = rv[j]*rv[j]*rv[j]*(1.f/128.f);
      dhv[j] = rv[j]*dn[n0l][j] - c3*dotv[j]*hD[n0l][j];
      *(u16*)(dh_s + tok*256 + swzb(tok, d*2)) = f2bf(dhv[j]);
    }
    *(uint2*)(dhT_s + d*64 + swz64(d, tok0*2)) =
        make_uint2(pack2(dhv[0], dhv[1]), pack2(dhv[2], dhv[3]));
  }
  __syncthreads();

  // ---- B1: SW1 partial [128 d][512 hid] = -(dh^T @ a), k=32 (one MFMA/tile) ----
  {
    int mh = w & 1, nh = w >> 1;
    s16x8 xD[4];
    #pragma unroll
    for (int mt = 0; mt < 4; ++mt){ int row = mh*64 + mt*16 + lr16;
      xD[mt] = *(const s16x8*)(dhT_s + row*64 + swz64(row, lg*16)); }
    s16x8 yB[8];
    #pragma unroll
    for (int n0l = 0; n0l < 8; ++n0l){
      int hid = nh*128 + n0l*16 + lr16;
      s16x8 v;
      #pragma unroll
      for (int e = 0; e < 8; ++e){ int tok = lg*8 + e;
        v[e] = *(const short*)(a_s + tok*1024 + swza(tok, hid*2)); }
      yB[n0l] = v;
    }
    #pragma unroll 2
    for (int mt = 0; mt < 4; ++mt){
      #pragma unroll
      for (int n0l = 0; n0l < 8; ++n0l){
        f32x4 acc = {0.f,0.f,0.f,0.f};
        acc = MFMA(xD[mt], yB[n0l], acc);
        int hid = nh*128 + n0l*16 + lr16;
        #pragma unroll
        for (int j = 0; j < 4; ++j)
          SW1p[bc*131072 + (size_t)th*65536 + (size_t)(mh*64 + mt*16 + lg*4 + j)*512 + hid] = f2bf(-acc[j]);
      }
    }
  }
  __syncthreads();   // a_s dead -> duT

  // ---- B2: duT[512 hid][32 tok] = (dh @ w1^T) * up ----
  {
    s16x8 xDh[2][4];
    #pragma unroll
    for (int mt = 0; mt < 2; ++mt){ int row = mt*16 + lr16;
      #pragma unroll
      for (int ks = 0; ks < 4; ++ks)
        xDh[mt][ks] = *(const s16x8*)(dh_s + row*256 + swzb(row, (ks*32+lg*8)*2)); }
    const u16* w1b = w1bf + (size_t)bh*65536;
    #pragma unroll
    for (int n0l = 0; n0l < 4; ++n0l){
      int hid = w*64 + n0l*16 + lr16;
      s16x8 yW[4];
      #pragma unroll
      for (int ks = 0; ks < 4; ++ks)
        yW[ks] = *(const s16x8*)(w1b + (size_t)hid*128 + ks*32 + lg*8);
      #pragma unroll
      for (int mt = 0; mt < 2; ++mt){
        f32x4 acc = {0.f,0.f,0.f,0.f};
        #pragma unroll
        for (int ks = 0; ks < 4; ++ks) acc = MFMA(xDh[mt][ks], yW[ks], acc);
        int tk0 = mt*16 + lg*4;
        uint2 ur = *(const uint2*)(upT_s + hid*64 + swz64(hid, tk0*2));
        float u0 = bf2f((u16)(ur.x & 0xffff)), u1 = bf2f((u16)(ur.x >> 16));
        float u2 = bf2f((u16)(ur.y & 0xffff)), u3 = bf2f((u16)(ur.y >> 16));
        *(uint2*)(duT_s + hid*64 + swz64(hid, tk0*2)) =
            make_uint2(pack2(acc[0]*u0, acc[1]*u1), pack2(acc[2]*u2, acc[3]*u3));
      }
    }
  }
  __syncthreads();   // upT dead -> kcT

  // ---- build kcT[128 d][32 tok] ----
  {
    int tok = t & 31, d0 = (t >> 5)*8;
    s16x8 kv = *(const s16x8*)(kc_g + (size_t)tok*128 + d0);
    #pragma unroll
    for (int e = 0; e < 8; ++e)
      *(u16*)(kcT_s + (d0+e)*64 + swz64(d0+e, tok*2)) = kv[e];
  }
  __syncthreads();

  // ---- B3: SW0 partial [512 hid][128 d] = -(duT @ kc), k=32 ----
  {
    s16x8 xU[4];
    #pragma unroll
    for (int mi = 0; mi < 4; ++mi){ int hid = w*64 + mi*16 + lr16;
      xU[mi] = *(const s16x8*)(duT_s + hid*64 + swz64(hid, lg*16)); }
    #pragma unroll 2
    for (int n0 = 0; n0 < 8; ++n0){
      int d = n0*16 + lr16;
      s16x8 yK = *(const s16x8*)(kcT_s + d*64 + swz64(d, lg*16));
      #pragma unroll
      for (int mi = 0; mi < 4; ++mi){
        f32x4 acc = {0.f,0.f,0.f,0.f};
        acc = MFMA(xU[mi], yK, acc);
        #pragma unroll
        for (int j = 0; j < 4; ++j)
          SW0p[bc*131072 + (size_t)th*65536 + (size_t)(w*64 + mi*16 + lg*4 + j)*128 + d] = f2bf(-acc[j]);
      }
    }
  }
}

// ---------------- scans (sum the two token-half partials; f32 state, bf16 storage) ----------------
__global__ __launch_bounds__(256) void k_scan(
    const u16* __restrict__ w0T, const u16* __restrict__ w1T, const float* __restrict__ mg,
    const u16* __restrict__ SW0p, const u16* __restrict__ SW1p, const float* __restrict__ SGp,
    const float* __restrict__ momb, const float* __restrict__ decb,
    u16* __restrict__ W0C, u16* __restrict__ W1C, float* __restrict__ GC){
  int bh = blockIdx.y;
  int e = blockIdx.x*256 + threadIdx.x;
  const float* momp = momb + bh*NCH;
  const float* decp = decb + bh*NCH;
  float m = 0.f, Wv;
  if (e < 65536){
    Wv = bf2f(w0T[(size_t)bh*65536 + e]);
    const u16* su = SW0p + (size_t)bh*NCH*131072 + e;
    u16* outp = W0C + (size_t)bh*NCH*65536 + e;
    for (int c = 0; c < NCH; ++c){
      outp[(size_t)c*65536] = f2bf(Wv);
      float sv = bf2f(su[(size_t)c*131072]) + bf2f(su[(size_t)c*131072 + 65536]);
      m = momp[c]*m + sv;
      Wv = (1.f - decp[c])*Wv + m;
    }
  } else if (e < 131072){
    int e2 = e - 65536;
    Wv = bf2f(w1T[(size_t)bh*65536 + e2]);
    const u16* su = SW1p + (size_t)bh*NCH*131072 + e2;
    u16* outp = W1C + (size_t)bh*NCH*65536 + e2;
    for (int c = 0; c < NCH; ++c){
      outp[(size_t)c*65536] = f2bf(Wv);
      float sv = bf2f(su[(size_t)c*131072]) + bf2f(su[(size_t)c*131072 + 65536]);
      m = momp[c]*m + sv;
      Wv = (1.f - decp[c])*Wv + m;
    }
  } else if (e < 131200){
    int e3 = e - 131072;
    Wv = mg[(size_t)bh*128 + e3];
    const float* su = SGp + (size_t)bh*NCH*256 + e3;
    float* outp = GC + (size_t)bh*NCH*128 + e3;
    for (int c = 0; c < NCH; ++c){
      outp[(size_t)c*128] = Wv;
      float sv = su[(size_t)c*256] + su[(size_t)c*256 + 128];
      m = momp[c]*m + sv;
      Wv = (1.f - decp[c])*Wv + m;
    }
  }
}

// ---------------- retrieval (512 threads, 8 waves, 66KB LDS -> 2 blocks/CU) ----------------
__global__ __launch_bounds__(512) void k_retr(
    const u16* __restrict__ Qc, const u16* __restrict__ W0C, const u16* __restrict__ W1C,
    const float* __restrict__ GC, const float* __restrict__ gate, u16* __restrict__ OH){
  extern __shared__ char sm[];
  char* a_s = sm;                      // [64][512] swza
  float* scr = (float*)(sm + 65536);   // [128]
  int c = blockIdx.x, bh = blockIdx.y, t = threadIdx.x;
  size_t bc = (size_t)bh*NCH + c;
  int l = t & 63, w = t >> 6, lr16 = l & 15, lg = l >> 4;
  int tg = w & 3, dhf = w >> 2;
  const u16* q_g = Qc + bc*8192;

  s16x8 xq[4];
  #pragma unroll
  for (int k = 0; k < 4; ++k)
    xq[k] = *(const s16x8*)(q_g + (size_t)(tg*16+lr16)*128 + k*32 + lg*8);
  const u16* w0c = W0C + bc*65536;
  for (int n0h = 0; n0h < 16; ++n0h){
    int n0 = dhf*16 + n0h;
    f32x4 acc = {0.f,0.f,0.f,0.f};
    const u16* yb = w0c + (size_t)(n0*16 + lr16)*128 + lg*8;
    #pragma unroll
    for (int k = 0; k < 4; ++k) acc = MFMA(xq[k], *(const s16x8*)(yb + k*32), acc);
    int hid = n0*16 + lr16;
    #pragma unroll
    for (int j = 0; j < 4; ++j){
      int tok = tg*16 + lg*4 + j;
      float u = acc[j];
      float av = u*0.5f*(1.f + erff(u*0.70710678118654752f));
      *(u16*)(a_s + tok*1024 + swza(tok, hid*2)) = f2bf(av);
    }
  }
  __syncthreads();
  s16x8 xa[16];
  #pragma unroll
  for (int k = 0; k < 16; ++k){ int row = tg*16 + lr16;
    xa[k] = *(const s16x8*)(a_s + row*1024 + swza(row, (k*32+lg*8)*2)); }
  const u16* w1c = W1C + bc*65536;
  f32x4 hD[4];
  #pragma unroll
  for (int n0l = 0; n0l < 4; ++n0l){
    int d = dhf*64 + n0l*16 + lr16;
    f32x4 acc = {0.f,0.f,0.f,0.f};
    const u16* yb = w1c + (size_t)d*512 + lg*8;
    #pragma unroll
    for (int k = 0; k < 16; ++k) acc = MFMA(xa[k], *(const s16x8*)(yb + k*32), acc);
    hD[n0l] = acc;
  }
  #pragma unroll
  for (int j = 0; j < 4; ++j){
    float s = 0.f;
    #pragma unroll
    for (int n0l = 0; n0l < 4; ++n0l) s += hD[n0l][j]*hD[n0l][j];
    s += __shfl_xor(s,1); s += __shfl_xor(s,2); s += __shfl_xor(s,4); s += __shfl_xor(s,8);
    if (lr16 == 0) scr[dhf*64 + tg*16 + lg*4 + j] = s;
  }
  __syncthreads();
  float rv[4], gtv[4];
  #pragma unroll
  for (int j = 0; j < 4; ++j){
    int tok = tg*16 + lg*4 + j;
    rv[j] = rsqrtf((scr[tok] + scr[64 + tok])*(1.f/128.f) + 1e-6f);
    gtv[j] = gate[(size_t)(c*64 + tok)*8 + bh];
  }
  #pragma unroll
  for (int n0l = 0; n0l < 4; ++n0l){
    int d = dhf*64 + n0l*16 + lr16;
    float g0 = GC[bc*128 + d];
    #pragma unroll
    for (int j = 0; j < 4; ++j){
      int tok = tg*16 + lg*4 + j; int tokg = c*64 + tok;
      float qv = bf2f(q_g[(size_t)tok*128 + d]);
      float p = hD[n0l][j]*rv[j]*g0 + qv;
      OH[(size_t)tokg*1024 + bh*128 + d] = f2bf(p*gtv[j]);
    }
  }
}

// ---------------- launch ----------------
extern "C" void kernel_launch(void* const* d_in, const int* in_sizes, int n_in,
                              void* d_out, int out_size, void* d_ws, size_t ws_size,
                              hipStream_t stream) {
  (void)in_sizes; (void)n_in; (void)out_size; (void)ws_size;
  const float* x     = (const float*)d_in[0];
  const float* snw   = (const float*)d_in[1];
  const float* rnw   = (const float*)d_in[2];
  const float* Wq    = (const float*)d_in[3];
  const float* Wk    = (const float*)d_in[4];
  const float* Wv    = (const float*)d_in[5];
  const float* Wstep = (const float*)d_in[6];
  const float* bstep = (const float*)d_in[7];
  const float* Wmom  = (const float*)d_in[8];
  const float* bmom  = (const float*)d_in[9];
  const float* Wdec  = (const float*)d_in[10];
  const float* bdec  = (const float*)d_in[11];
  const float* gateW = (const float*)d_in[12];
  const float* combW = (const float*)d_in[13];
  const float* mw0   = (const float*)d_in[14];
  const float* mw1   = (const float*)d_in[15];
  const float* mg    = (const float*)d_in[16];
  float* out = (float*)d_out;

  char* Wb = (char*)d_ws;
  // live-range-aliased layout (208MB peak):
  u16* Qc    = (u16*)(Wb + 0*MB);    // live: gemm3 -> retr
  u16* s_bf  = (u16*)(Wb + 4*MB);    // dead after gemm3
  u16* r_bf  = (u16*)(Wb + 8*MB);    // dead after gemm3
  u16* Kc    = (u16*)(Wb + 12*MB);   // dead after grad
  u16* Vc    = (u16*)(Wb + 16*MB);   // dead after grad
  u16* W0C   = (u16*)(Wb + 4*MB);    // written by scan (overlays s/r/K/V + 20..36)
  u16* W1C   = (u16*)(Wb + 36*MB);
  u16* WqT   = (u16*)(Wb + 68*MB);
  u16* WkT   = (u16*)(Wb + 70*MB);
  u16* WvT   = (u16*)(Wb + 72*MB);
  u16* combT = (u16*)(Wb + 74*MB);
  u16* w0T   = (u16*)(Wb + 76*MB);
  u16* w1T   = (u16*)(Wb + 77*MB);
  u16* w1bf  = (u16*)(Wb + 78*MB);
  float* pooled = (float*)(Wb + 79*MB);
  float* lrc    = (float*)(Wb + 79*MB + 131072);
  float* momb   = (float*)(Wb + 79*MB + 196608);
  float* decb   = (float*)(Wb + 79*MB + 197632);
  float* gate   = (float*)(Wb + 79*MB + 198656);
  float* GC     = (float*)(Wb + 79*MB + 264192);
  float* SGp    = (float*)(Wb + 79*MB + 395264);   // 256KB
  u16* SW0p  = (u16*)(Wb + 80*MB);   // 64MB, dead after scan
  u16* SW1p  = (u16*)(Wb + 144*MB);  // 64MB, dead after scan
  u16* OH    = (u16*)(Wb + 80*MB);   // written by retr (overlays SW0p)

  hipFuncSetAttribute((const void*)k_grad, hipFuncAttributeMaxDynamicSharedMemorySize, 81920);
  hipFuncSetAttribute((const void*)k_retr, hipFuncAttributeMaxDynamicSharedMemorySize, 66560);

  k_rmsnorm<<<2048, 256, 0, stream>>>(x, snw, rnw, s_bf, r_bf);
  k_pool<<<dim3(32,4), 256, 0, stream>>>(s_bf, pooled);
  k_lrgate<<<512, 256, 0, stream>>>(s_bf, r_bf, Wstep, bstep, gateW, lrc, gate);
  k_momdec<<<32, 64, 0, stream>>>(pooled, Wmom, bmom, Wdec, bdec, momb, decb);
  k_trf4<<<dim3(32,32,4), 256, 0, stream>>>(Wq, Wk, Wv, combW, WqT, WkT, WvT, combT);
  k_trf<<<dim3(16,4,8), 256, 0, stream>>>(mw0, w0T, 128, 512);
  k_trf<<<dim3(4,16,8), 256, 0, stream>>>(mw1, w1T, 512, 128);
  k_cast<<<2048, 256, 0, stream>>>(mw1, w1bf, 524288);
  k_gemm3<<<dim3(32,16,3), 256, 0, stream>>>(s_bf, r_bf, WkT, WvT, WqT, Kc, Vc, Qc);
  k_grad<<<dim3(64,8), 512, 81920, stream>>>(Kc, Vc, lrc, w0T, w1T, w1bf, mg, SW0p, SW1p, SGp);
  k_scan<<<dim3(513,8), 256, 0, stream>>>(w0T, w1T, mg, SW0p, SW1p, SGp, momb, decb, W0C, W1C, GC);
  k_retr<<<dim3(32,8), 512, 66560, stream>>>(Qc, W0C, W1C, GC, gate, OH);
  k_gemm_bf<<<dim3(32,16), 256, 0, stream>>>(OH, combT, (void*)out, 0);
}

// Round 7
// 271.482 us; speedup vs baseline: 1.5997x; 1.1790x over previous
//
#include <hip/hip_runtime.h>
#include <hip/hip_bf16.h>
#include <math.h>

#define NH   8
#define DHD  128
#define HIDN 512
#define CHK  64
#define NCH  32
#define MB   1048576ull

typedef unsigned short u16;
typedef unsigned int   u32;
typedef short s16x8 __attribute__((ext_vector_type(8)));
typedef float f32x4 __attribute__((ext_vector_type(4)));

#define MFMA(a,b,c) __builtin_amdgcn_mfma_f32_16x16x32_bf16((a),(b),(c),0,0,0)

__device__ __forceinline__ float bf2f(u16 v){ return __uint_as_float(((u32)v) << 16); }
__device__ __forceinline__ u16 f2bf(float f){
  u32 u = __float_as_uint(f);
  u += 0x7fffu + ((u >> 16) & 1u);
  return (u16)(u >> 16);
}
__device__ __forceinline__ u32 pack2(float a, float b){
  return (u32)f2bf(a) | ((u32)f2bf(b) << 16);
}
__device__ __forceinline__ float waveRedSum(float v){
  #pragma unroll
  for (int off = 32; off; off >>= 1) v += __shfl_xor(v, off);
  return v;
}
// swizzles
__device__ __forceinline__ int swzb(int row, int colb){ return colb ^ ((row & 7) << 4); }
__device__ __forceinline__ int swza(int row, int colb){
  return colb ^ ((row & 7) << 4) ^ (((row >> 3) & 3) << 5);
}

// Fragment-major weight layouts (1KB contiguous per 16x32 MFMA B-tile, lane l owns bytes l*16):
//  L0  (n=hid 32 tiles, k=d 4 blocks):  addr(hid,d) = ((hid>>4)*4  + (d>>5) )*512 + ((d>>3)&3)*128  + (hid&15)*8 + (d&7)
//  L1  (n=d 8 tiles,   k=hid 16 blk):   addr(d,hid) = ((d>>4)*16  + (hid>>5))*512 + ((hid>>3)&3)*128 + (d&15)*8  + (hid&7)
//  L1b (n=hid 32 tiles, k=d 4 blocks):  same index form as L0 but stores w1[hid][d]

// ---------------- prep ----------------

__global__ __launch_bounds__(256) void k_rmsnorm(const float* __restrict__ x,
    const float* __restrict__ wst, const float* __restrict__ wrt,
    u16* __restrict__ s_bf, u16* __restrict__ r_bf){
  int row = blockIdx.x, t = threadIdx.x;
  float4 v = ((const float4*)(x + (size_t)row*1024))[t];
  float ss = v.x*v.x + v.y*v.y + v.z*v.z + v.w*v.w;
  ss = waveRedSum(ss);
  __shared__ float red[4];
  int wv = t >> 6, ln = t & 63;
  if (ln == 0) red[wv] = ss;
  __syncthreads();
  float rr = rsqrtf((red[0]+red[1]+red[2]+red[3])*(1.f/1024.f) + 1e-6f);
  float4 a = ((const float4*)wst)[t];
  float4 b = ((const float4*)wrt)[t];
  uint2 so = make_uint2(pack2(v.x*rr*a.x, v.y*rr*a.y), pack2(v.z*rr*a.z, v.w*rr*a.w));
  uint2 ro = make_uint2(pack2(v.x*rr*b.x, v.y*rr*b.y), pack2(v.z*rr*b.z, v.w*rr*b.w));
  *(uint2*)(s_bf + (size_t)row*1024 + t*4) = so;
  *(uint2*)(r_bf + (size_t)row*1024 + t*4) = ro;
}

__global__ __launch_bounds__(256) void k_pool(const u16* __restrict__ s_bf, float* __restrict__ pooled){
  int c = blockIdx.x; int d = blockIdx.y*256 + threadIdx.x;
  float acc = 0.f;
  for (int tt = 0; tt < 64; ++tt) acc += bf2f(s_bf[((size_t)c*64+tt)*1024 + d]);
  pooled[(size_t)c*1024 + d] = acc * (1.f/64.f);
}

__global__ __launch_bounds__(256) void k_lrgate(const u16* __restrict__ s_bf, const u16* __restrict__ r_bf,
    const float* __restrict__ Wstep, const float* __restrict__ bstep,
    const float* __restrict__ gateW,
    float* __restrict__ lrc, float* __restrict__ gate){
  int wv = threadIdx.x >> 6, ln = threadIdx.x & 63;
  int tok = blockIdx.x*4 + wv;
  const u16* srow = s_bf + (size_t)tok*1024;
  const u16* rrow = r_bf + (size_t)tok*1024;
  for (int o = 0; o < 16; ++o){
    int h = o & 7;
    const u16* src = (o < 8) ? srow : rrow;
    const float* W = (o < 8) ? Wstep : gateW;
    float acc = 0.f;
    for (int k = ln; k < 1024; k += 64) acc += bf2f(src[k])*W[(size_t)k*8+h];
    acc = waveRedSum(acc);
    if (ln == 0){
      if (o < 8){
        float v = 1.f/(1.f+expf(-(acc + bstep[h])));
        lrc[((size_t)h*NCH + (tok>>6))*CHK + (tok&63)] = v;
      } else {
        gate[(size_t)tok*8 + h] = 1.f/(1.f+expf(-acc));
      }
    }
  }
}

__global__ __launch_bounds__(64) void k_momdec(const float* __restrict__ pooled,
    const float* __restrict__ Wmom, const float* __restrict__ bmom,
    const float* __restrict__ Wdec, const float* __restrict__ bdec,
    float* __restrict__ momb, float* __restrict__ decb){
  int c = blockIdx.x, ln = threadIdx.x;
  const float* prow = pooled + (size_t)c*1024;
  for (int o = 0; o < 16; ++o){
    int h = o & 7;
    const float* W = (o < 8) ? Wmom : Wdec;
    float acc = 0.f;
    for (int k = ln; k < 1024; k += 64) acc += prow[k]*W[(size_t)k*8+h];
    acc = waveRedSum(acc);
    if (ln == 0){
      float bb = (o < 8) ? bmom[h] : bdec[h];
      float v = 1.f/(1.f+expf(-(acc+bb)));
      if (o < 8) momb[h*NCH + c] = v; else decb[h*NCH + c] = v;
    }
  }
}

// 4 fused 1024x1024 f32->bf16 transposes
__global__ __launch_bounds__(256) void k_trf4(
    const float* __restrict__ A0, const float* __restrict__ A1,
    const float* __restrict__ A2, const float* __restrict__ A3,
    u16* __restrict__ O0, u16* __restrict__ O1, u16* __restrict__ O2, u16* __restrict__ O3){
  __shared__ u16 tile[32][34];
  int z = blockIdx.z;
  const float* in = (z==0)?A0:(z==1)?A1:(z==2)?A2:A3;
  u16* out = (z==0)?O0:(z==1)?O1:(z==2)?O2:O3;
  int c0 = blockIdx.x*32, r0 = blockIdx.y*32;
  int tx = threadIdx.x & 31, ty = threadIdx.x >> 5;
  #pragma unroll
  for (int k = 0; k < 4; ++k) tile[ty+k*8][tx] = f2bf(in[(size_t)(r0+ty+k*8)*1024 + c0+tx]);
  __syncthreads();
  #pragma unroll
  for (int k = 0; k < 4; ++k) out[(size_t)(c0+ty+k*8)*1024 + r0+tx] = tile[tx][ty+k*8];
}

// pack mem weights into fragment-major layouts (y: 0=w0L, 1=w1L, 2=w1bL)
__global__ __launch_bounds__(256) void k_packw(const float* __restrict__ mw0, const float* __restrict__ mw1,
    u16* __restrict__ w0L, u16* __restrict__ w1L, u16* __restrict__ w1bL){
  int h = blockIdx.z, which = blockIdx.y;
  int i = blockIdx.x*256 + threadIdx.x;
  int r = i & 511, blk = i >> 9;
  int lg = r >> 7, lr = (r >> 3) & 15, e = r & 7;
  float v; u16* dst;
  if (which == 0){ int n0 = blk >> 2, ks = blk & 3; int hid = n0*16+lr, d = ks*32+lg*8+e;
    v = mw0[(size_t)h*65536 + (size_t)d*512 + hid]; dst = w0L; }
  else if (which == 1){ int n0 = blk >> 4, ks = blk & 15; int d = n0*16+lr, hid = ks*32+lg*8+e;
    v = mw1[(size_t)h*65536 + (size_t)hid*128 + d]; dst = w1L; }
  else { int n0 = blk >> 2, ks = blk & 3; int hid = n0*16+lr, d = ks*32+lg*8+e;
    v = mw1[(size_t)h*65536 + (size_t)hid*128 + d]; dst = w1bL; }
  dst[(size_t)h*65536 + i] = f2bf(v);
}

// ---------------- MFMA GEMM body: M=2048,N=1024,K=1024 ----------------
__device__ __forceinline__ void gemm_body(const u16* __restrict__ A, const u16* __restrict__ BT,
    void* __restrict__ Cp, int mode){
  __shared__ char As[8192];
  __shared__ char Bs[8192];
  int t = threadIdx.x; int l = t & 63, w = t >> 6, lr16 = l & 15, lg = l >> 4;
  int bm = blockIdx.x*64, bn = blockIdx.y*64;
  f32x4 acc[4];
  #pragma unroll
  for (int mt = 0; mt < 4; ++mt) acc[mt] = (f32x4){0.f,0.f,0.f,0.f};
  for (int k0 = 0; k0 < 1024; k0 += 64){
    #pragma unroll
    for (int i = 0; i < 2; ++i){ int e = (i*256+t)*8; int row = e>>6, col = e&63;
      *(s16x8*)(As + row*128 + swzb(row, col*2)) = *(const s16x8*)(A + (size_t)(bm+row)*1024 + k0 + col);
      *(s16x8*)(Bs + row*128 + swzb(row, col*2)) = *(const s16x8*)(BT + (size_t)(bn+row)*1024 + k0 + col); }
    __syncthreads();
    #pragma unroll
    for (int ks = 0; ks < 2; ++ks){
      int rowb = w*16 + lr16;
      s16x8 y = *(const s16x8*)(Bs + rowb*128 + swzb(rowb, (ks*32+lg*8)*2));
      #pragma unroll
      for (int mt = 0; mt < 4; ++mt){ int row = mt*16 + lr16;
        s16x8 xa = *(const s16x8*)(As + row*128 + swzb(row, (ks*32+lg*8)*2));
        acc[mt] = MFMA(xa, y, acc[mt]); }
    }
    __syncthreads();
  }
  #pragma unroll
  for (int mt = 0; mt < 4; ++mt)
    #pragma unroll
    for (int j = 0; j < 4; ++j){
      int row = bm + mt*16 + lg*4 + j;
      int coln = bn + w*16 + lr16;
      if (mode == 0) ((float*)Cp)[(size_t)row*1024 + coln] = acc[mt][j];
      else { int cI = row>>6, tok = row&63, h = coln>>7, d = coln&127;
        ((u16*)Cp)[((size_t)(h*32+cI)*64 + tok)*128 + d] = f2bf(acc[mt][j]); }
    }
}

__global__ __launch_bounds__(256) void k_gemm_bf(const u16* __restrict__ A, const u16* __restrict__ BT,
    void* __restrict__ Cp, int mode){ gemm_body(A, BT, Cp, mode); }

__global__ __launch_bounds__(256) void k_gemm3(
    const u16* __restrict__ s_bf, const u16* __restrict__ r_bf,
    const u16* __restrict__ WkT, const u16* __restrict__ WvT, const u16* __restrict__ WqT,
    u16* __restrict__ Kc, u16* __restrict__ Vc, u16* __restrict__ Qc){
  int z = blockIdx.z;
  const u16* A = (z==2) ? r_bf : s_bf;
  const u16* BT = (z==0) ? WkT : (z==1) ? WvT : WqT;
  u16* C = (z==0) ? Kc : (z==1) ? Vc : Qc;
  gemm_body(A, BT, (void*)C, 1);
}

// ---------------- fused gradient (512 threads, r4 structure + coalesced L-layout stores) ----------------
// LDS (160KB): a[64][1024B] swza (B1 staging after barrier; then duT [512][128B])
//            | upT[512][128B] swzb (-> kcT[128][128B] after B2)
//            | dh[64][256B] swzb (scr first 3KB; B3 staging after B2) | dhT[128][128B] swzb (B3 staging too)
__global__ __launch_bounds__(512) void k_grad(
    const u16* __restrict__ Kc, const u16* __restrict__ Vc, const float* __restrict__ lrc,
    const u16* __restrict__ w0L, const u16* __restrict__ w1L, const u16* __restrict__ w1bL,
    const float* __restrict__ mg,
    u16* __restrict__ SW0, u16* __restrict__ SW1, float* __restrict__ SG){
  extern __shared__ char sm[];
  char* a_s   = sm;            // 64KB
  char* upT_s = sm + 65536;    // 64KB
  char* dh_s  = sm + 131072;   // 16KB
  char* dhT_s = sm + 147456;   // 16KB
  char* duT_s = a_s;           // alias after B1
  char* kcT_s = upT_s;         // alias after B2
  char* stg3  = dh_s;          // B3 staging region (dh+dhT 32KB, dead after B2)
  float* scr  = (float*)dh_s;  // ssq[0..127], dot[128..255], dga[256..767]

  int c = blockIdx.x, bh = blockIdx.y, t = threadIdx.x;
  size_t bc = (size_t)bh*NCH + c;
  int l = t & 63, w = t >> 6, lr16 = l & 15, lg = l >> 4;
  int tg = w & 3, dhf = w >> 2;
  int tokb = tg*16, tok0 = tokb + lg*4;

  const u16* kc_g = Kc + bc*8192;
  const u16* vc_g = Vc + bc*8192;

  // ---- P2: u = kc @ w0 ; a -> a_s ; gelu' -> upT_s ----
  s16x8 xk[4];
  #pragma unroll
  for (int k = 0; k < 4; ++k)
    xk[k] = *(const s16x8*)(kc_g + (size_t)(tokb+lr16)*128 + k*32 + lg*8);
  const u16* w0Lh = w0L + (size_t)bh*65536;
  for (int n0h = 0; n0h < 16; ++n0h){
    int n0 = dhf*16 + n0h;
    f32x4 acc = {0.f,0.f,0.f,0.f};
    const u16* yb = w0Lh + (size_t)n0*2048 + l*8;
    #pragma unroll
    for (int k = 0; k < 4; ++k) acc = MFMA(xk[k], *(const s16x8*)(yb + k*512), acc);
    int hid = n0*16 + lr16;
    float upv[4];
    #pragma unroll
    for (int j = 0; j < 4; ++j){
      int tok = tok0 + j;
      float u = acc[j];
      float cdf = 0.5f*(1.f + erff(u*0.70710678118654752f));
      upv[j] = cdf + u*0.3989422804014327f*expf(-0.5f*u*u);
      *(u16*)(a_s + tok*1024 + swza(tok, hid*2)) = f2bf(u*cdf);
    }
    *(uint2*)(upT_s + hid*128 + swzb(hid, tok0*2)) =
        make_uint2(pack2(upv[0], upv[1]), pack2(upv[2], upv[3]));
  }
  __syncthreads();

  // ---- P3: h = a @ w1 (toks tg, d range dhf*64..+63), rmsnorm fwd+bwd ----
  s16x8 xa[16];
  #pragma unroll
  for (int k = 0; k < 16; ++k){ int row = tokb + lr16;
    xa[k] = *(const s16x8*)(a_s + row*1024 + swza(row, (k*32+lg*8)*2)); }
  const u16* w1Lh = w1L + (size_t)bh*65536;
  f32x4 hD[4];
  #pragma unroll
  for (int n0l = 0; n0l < 4; ++n0l){
    f32x4 acc = {0.f,0.f,0.f,0.f};
    const u16* yb = w1Lh + (size_t)(dhf*4 + n0l)*8192 + l*8;
    #pragma unroll
    for (int k = 0; k < 16; ++k) acc = MFMA(xa[k], *(const s16x8*)(yb + k*512), acc);
    hD[n0l] = acc;
  }
  #pragma unroll
  for (int j = 0; j < 4; ++j){
    float s = 0.f;
    #pragma unroll
    for (int n0l = 0; n0l < 4; ++n0l) s += hD[n0l][j]*hD[n0l][j];
    s += __shfl_xor(s,1); s += __shfl_xor(s,2); s += __shfl_xor(s,4); s += __shfl_xor(s,8);
    if (lr16 == 0) scr[dhf*64 + tok0 + j] = s;
  }
  __syncthreads();
  float rv[4], lrv[4], dotp[4];
  #pragma unroll
  for (int j = 0; j < 4; ++j){
    int tok = tok0 + j;
    float tot = scr[tok] + scr[64 + tok];
    rv[j] = rsqrtf(tot*(1.f/128.f) + 1e-6f);
    lrv[j] = lrc[bc*64 + tok];
    dotp[j] = 0.f;
  }
  float dn[4][4];
  #pragma unroll
  for (int n0l = 0; n0l < 4; ++n0l){
    int d = dhf*64 + n0l*16 + lr16;
    float g0 = mg[(size_t)bh*128 + d];
    float dgav = 0.f;
    #pragma unroll
    for (int j = 0; j < 4; ++j){
      int tok = tok0 + j;
      float h = hD[n0l][j];
      float nrm = h*rv[j];
      float kcv = bf2f(kc_g[(size_t)tok*128 + d]);
      float vcv = bf2f(vc_g[(size_t)tok*128 + d]);
      float p = nrm*g0 + kcv;
      float dp = (2.f/128.f)*lrv[j]*(p - vcv);
      dgav += dp*nrm;
      float dnv = dp*g0;
      dn[n0l][j] = dnv;
      dotp[j] += dnv*h;
    }
    dgav += __shfl_xor(dgav,16); dgav += __shfl_xor(dgav,32);
    if (lg == 0) scr[256 + w*64 + n0l*16 + lr16] = dgav;
  }
  #pragma unroll
  for (int j = 0; j < 4; ++j){
    float dd = dotp[j];
    dd += __shfl_xor(dd,1); dd += __shfl_xor(dd,2); dd += __shfl_xor(dd,4); dd += __shfl_xor(dd,8);
    if (lr16 == 0) scr[128 + dhf*64 + tok0 + j] = dd;
  }
  __syncthreads();
  float dotv[4];
  #pragma unroll
  for (int j = 0; j < 4; ++j){
    int tok = tok0 + j;
    dotv[j] = scr[128 + tok] + scr[128 + 64 + tok];
  }
  if (t < 128){
    int dh2 = t >> 6, dl = t & 63;
    float s = scr[256 + (dh2*4+0)*64 + dl] + scr[256 + (dh2*4+1)*64 + dl]
            + scr[256 + (dh2*4+2)*64 + dl] + scr[256 + (dh2*4+3)*64 + dl];
    SG[bc*128 + t] = -s;
  }
  __syncthreads();   // scratch consumed; dh region writable
  #pragma unroll
  for (int n0l = 0; n0l < 4; ++n0l){
    int d = dhf*64 + n0l*16 + lr16;
    float dhv[4];
    #pragma unroll
    for (int j = 0; j < 4; ++j){
      int tok = tok0 + j;
      float c3 = rv[j]*rv[j]*rv[j]*(1.f/128.f);
      dhv[j] = rv[j]*dn[n0l][j] - c3*dotv[j]*hD[n0l][j];
      *(u16*)(dh_s + tok*256 + swzb(tok, d*2)) = f2bf(dhv[j]);
    }
    *(uint2*)(dhT_s + d*128 + swzb(d, tok0*2)) =
        make_uint2(pack2(dhv[0], dhv[1]), pack2(dhv[2], dhv[3]));
  }
  __syncthreads();

  // ---- B1: SW1 (L1 layout) = -(dh^T @ a). wave: hid range w*64..+63, all 128 d ----
  {
    s16x8 yB[4][2];
    #pragma unroll
    for (int n0l = 0; n0l < 4; ++n0l){
      int hid = w*64 + n0l*16 + lr16;
      #pragma unroll
      for (int ks = 0; ks < 2; ++ks){
        s16x8 v;
        #pragma unroll
        for (int e = 0; e < 8; ++e){ int tok = ks*32 + lg*8 + e;
          v[e] = *(const short*)(a_s + tok*1024 + swza(tok, hid*2)); }
        yB[n0l][ks] = v;
      }
    }
    __syncthreads();   // all a_s reads complete -> a_s usable as staging
    u16* stg = (u16*)(a_s + w*8192);
    #pragma unroll 1
    for (int half = 0; half < 2; ++half){
      #pragma unroll
      for (int mt4 = 0; mt4 < 4; ++mt4){
        int mt = half*4 + mt4; int row = mt*16 + lr16;
        s16x8 xD0 = *(const s16x8*)(dhT_s + row*128 + swzb(row, (lg*8)*2));
        s16x8 xD1 = *(const s16x8*)(dhT_s + row*128 + swzb(row, (32+lg*8)*2));
        #pragma unroll
        for (int n0l = 0; n0l < 4; ++n0l){
          f32x4 acc = {0.f,0.f,0.f,0.f};
          acc = MFMA(xD0, yB[n0l][0], acc);
          acc = MFMA(xD1, yB[n0l][1], acc);
          int base = mt4*1024 + (n0l>>1)*512 + (((n0l*2)+(lr16>>3))&3)*128 + (lr16&7);
          #pragma unroll
          for (int j = 0; j < 4; ++j)
            stg[base + (lg*4+j)*8] = f2bf(-acc[j]);
        }
      }
      asm volatile("s_waitcnt lgkmcnt(0)" ::: "memory");
      #pragma unroll
      for (int mt4 = 0; mt4 < 4; ++mt4){
        int mt = half*4 + mt4;
        u16* gb = SW1 + bc*65536 + (size_t)(mt*16 + w*2)*512;
        s16x8 o0 = *(const s16x8*)(stg + mt4*1024 + l*16);
        s16x8 o1 = *(const s16x8*)(stg + mt4*1024 + l*16 + 8);
        *(s16x8*)(gb + l*16) = o0;
        *(s16x8*)(gb + l*16 + 8) = o1;
      }
    }
  }
  __syncthreads();   // a_s dead -> duT

  // ---- B2: duT[512 hid][64 tok] = (dh @ w1^T) * up ----
  {
    s16x8 xDh[4][4];
    #pragma unroll
    for (int mt = 0; mt < 4; ++mt){ int row = mt*16 + lr16;
      #pragma unroll
      for (int ks = 0; ks < 4; ++ks)
        xDh[mt][ks] = *(const s16x8*)(dh_s + row*256 + swzb(row, (ks*32+lg*8)*2)); }
    const u16* w1bh = w1bL + (size_t)bh*65536;
    #pragma unroll 2
    for (int n0l = 0; n0l < 4; ++n0l){
      int hid = w*64 + n0l*16 + lr16;
      s16x8 yW[4];
      const u16* xb = w1bh + (size_t)(w*4 + n0l)*2048 + l*8;
      #pragma unroll
      for (int ks = 0; ks < 4; ++ks)
        yW[ks] = *(const s16x8*)(xb + ks*512);
      #pragma unroll
      for (int mt = 0; mt < 4; ++mt){
        f32x4 acc = {0.f,0.f,0.f,0.f};
        #pragma unroll
        for (int ks = 0; ks < 4; ++ks) acc = MFMA(xDh[mt][ks], yW[ks], acc);
        int tk0 = mt*16 + lg*4;
        uint2 ur = *(const uint2*)(upT_s + hid*128 + swzb(hid, tk0*2));
        float u0 = bf2f((u16)(ur.x & 0xffff)), u1 = bf2f((u16)(ur.x >> 16));
        float u2 = bf2f((u16)(ur.y & 0xffff)), u3 = bf2f((u16)(ur.y >> 16));
        *(uint2*)(duT_s + hid*128 + swzb(hid, tk0*2)) =
            make_uint2(pack2(acc[0]*u0, acc[1]*u1), pack2(acc[2]*u2, acc[3]*u3));
      }
    }
  }
  __syncthreads();   // upT dead -> kcT ; dh/dhT dead -> B3 staging

  // ---- build kcT[128 d][64 tok] ----
  #pragma unroll
  for (int i = 0; i < 2; ++i){
    int idx = i*512 + t;
    int tok = idx & 63, d0 = (idx >> 6)*8;
    s16x8 kv = *(const s16x8*)(kc_g + (size_t)tok*128 + d0);
    #pragma unroll
    for (int e = 0; e < 8; ++e)
      *(u16*)(kcT_s + (d0+e)*128 + swzb(d0+e, tok*2)) = kv[e];
  }
  __syncthreads();

  // ---- B3: SW0 (L0 layout) = -(duT @ kc). wave: hid range w*64..+63, all 128 d ----
  {
    s16x8 yK[8][2];
    #pragma unroll
    for (int n0 = 0; n0 < 8; ++n0){
      int d = n0*16 + lr16;
      #pragma unroll
      for (int ks = 0; ks < 2; ++ks)
        yK[n0][ks] = *(const s16x8*)(kcT_s + d*128 + swzb(d, (ks*32+lg*8)*2));
    }
    u16* stg = (u16*)(stg3 + w*4096);
    #pragma unroll 1
    for (int mi = 0; mi < 4; ++mi){
      int hid = w*64 + mi*16 + lr16;
      s16x8 xU0 = *(const s16x8*)(duT_s + hid*128 + swzb(hid, (lg*8)*2));
      s16x8 xU1 = *(const s16x8*)(duT_s + hid*128 + swzb(hid, (32+lg*8)*2));
      #pragma unroll
      for (int n0 = 0; n0 < 8; ++n0){
        f32x4 acc = {0.f,0.f,0.f,0.f};
        acc = MFMA(xU0, yK[n0][0], acc);
        acc = MFMA(xU1, yK[n0][1], acc);
        int base = (n0>>1)*512 + (((n0*2)+(lr16>>3))&3)*128 + (lr16&7);
        #pragma unroll
        for (int j = 0; j < 4; ++j)
          stg[base + (lg*4+j)*8] = f2bf(-acc[j]);
      }
      asm volatile("s_waitcnt lgkmcnt(0)" ::: "memory");
      u16* gb = SW0 + bc*65536 + (size_t)(w*4 + mi)*2048;
      #pragma unroll
      for (int q = 0; q < 4; ++q){
        s16x8 o = *(const s16x8*)(stg + l*32 + q*8);
        *(s16x8*)(gb + l*32 + q*8) = o;
      }
    }
  }
}

// ---------------- scans (layouts are linear-opaque; f32 state, bf16 storage) ----------------
__global__ __launch_bounds__(256) void k_scan(
    const u16* __restrict__ w0L, const u16* __restrict__ w1L, const float* __restrict__ mg,
    const u16* __restrict__ SW0, const u16* __restrict__ SW1, const float* __restrict__ SG,
    const float* __restrict__ momb, const float* __restrict__ decb,
    u16* __restrict__ W0C, u16* __restrict__ W1C, float* __restrict__ GC){
  int bh = blockIdx.y;
  int e = blockIdx.x*256 + threadIdx.x;
  const float* momp = momb + bh*NCH;
  const float* decp = decb + bh*NCH;
  float m = 0.f, Wv;
  if (e < 65536){
    Wv = bf2f(w0L[(size_t)bh*65536 + e]);
    const u16* su = SW0 + (size_t)bh*NCH*65536 + e;
    u16* outp = W0C + (size_t)bh*NCH*65536 + e;
    for (int c = 0; c < NCH; ++c){
      outp[(size_t)c*65536] = f2bf(Wv);
      m = momp[c]*m + bf2f(su[(size_t)c*65536]);
      Wv = (1.f - decp[c])*Wv + m;
    }
  } else if (e < 131072){
    int e2 = e - 65536;
    Wv = bf2f(w1L[(size_t)bh*65536 + e2]);
    const u16* su = SW1 + (size_t)bh*NCH*65536 + e2;
    u16* outp = W1C + (size_t)bh*NCH*65536 + e2;
    for (int c = 0; c < NCH; ++c){
      outp[(size_t)c*65536] = f2bf(Wv);
      m = momp[c]*m + bf2f(su[(size_t)c*65536]);
      Wv = (1.f - decp[c])*Wv + m;
    }
  } else if (e < 131200){
    int e3 = e - 131072;
    Wv = mg[(size_t)bh*128 + e3];
    const float* su = SG + (size_t)bh*NCH*128 + e3;
    float* outp = GC + (size_t)bh*NCH*128 + e3;
    for (int c = 0; c < NCH; ++c){
      outp[(size_t)c*128] = Wv;
      m = momp[c]*m + su[(size_t)c*128];
      Wv = (1.f - decp[c])*Wv + m;
    }
  }
}

// ---------------- retrieval (512 threads; weights in L0/L1 -> coalesced frag reads) ----------------
__global__ __launch_bounds__(512) void k_retr(
    const u16* __restrict__ Qc, const u16* __restrict__ W0C, const u16* __restrict__ W1C,
    const float* __restrict__ GC, const float* __restrict__ gate, u16* __restrict__ OH){
  extern __shared__ char sm[];
  char* a_s = sm;                      // [64][1024B] swza
  float* scr = (float*)(sm + 65536);   // [128]
  int c = blockIdx.x, bh = blockIdx.y, t = threadIdx.x;
  size_t bc = (size_t)bh*NCH + c;
  int l = t & 63, w = t >> 6, lr16 = l & 15, lg = l >> 4;
  int tg = w & 3, dhf = w >> 2;
  const u16* q_g = Qc + bc*8192;

  s16x8 xq[4];
  #pragma unroll
  for (int k = 0; k < 4; ++k)
    xq[k] = *(const s16x8*)(q_g + (size_t)(tg*16+lr16)*128 + k*32 + lg*8);
  const u16* w0c = W0C + bc*65536;
  for (int n0h = 0; n0h < 16; ++n0h){
    int n0 = dhf*16 + n0h;
    f32x4 acc = {0.f,0.f,0.f,0.f};
    const u16* yb = w0c + (size_t)n0*2048 + l*8;
    #pragma unroll
    for (int k = 0; k < 4; ++k) acc = MFMA(xq[k], *(const s16x8*)(yb + k*512), acc);
    int hid = n0*16 + lr16;
    #pragma unroll
    for (int j = 0; j < 4; ++j){
      int tok = tg*16 + lg*4 + j;
      float u = acc[j];
      float av = u*0.5f*(1.f + erff(u*0.70710678118654752f));
      *(u16*)(a_s + tok*1024 + swza(tok, hid*2)) = f2bf(av);
    }
  }
  __syncthreads();
  s16x8 xa[16];
  #pragma unroll
  for (int k = 0; k < 16; ++k){ int row = tg*16 + lr16;
    xa[k] = *(const s16x8*)(a_s + row*1024 + swza(row, (k*32+lg*8)*2)); }
  const u16* w1c = W1C + bc*65536;
  f32x4 hD[4];
  #pragma unroll
  for (int n0l = 0; n0l < 4; ++n0l){
    f32x4 acc = {0.f,0.f,0.f,0.f};
    const u16* yb = w1c + (size_t)(dhf*4 + n0l)*8192 + l*8;
    #pragma unroll
    for (int k = 0; k < 16; ++k) acc = MFMA(xa[k], *(const s16x8*)(yb + k*512), acc);
    hD[n0l] = acc;
  }
  #pragma unroll
  for (int j = 0; j < 4; ++j){
    float s = 0.f;
    #pragma unroll
    for (int n0l = 0; n0l < 4; ++n0l) s += hD[n0l][j]*hD[n0l][j];
    s += __shfl_xor(s,1); s += __shfl_xor(s,2); s += __shfl_xor(s,4); s += __shfl_xor(s,8);
    if (lr16 == 0) scr[dhf*64 + tg*16 + lg*4 + j] = s;
  }
  __syncthreads();
  float rv[4], gtv[4];
  #pragma unroll
  for (int j = 0; j < 4; ++j){
    int tok = tg*16 + lg*4 + j;
    rv[j] = rsqrtf((scr[tok] + scr[64 + tok])*(1.f/128.f) + 1e-6f);
    gtv[j] = gate[(size_t)(c*64 + tok)*8 + bh];
  }
  #pragma unroll
  for (int n0l = 0; n0l < 4; ++n0l){
    int d = dhf*64 + n0l*16 + lr16;
    float g0 = GC[bc*128 + d];
    #pragma unroll
    for (int j = 0; j < 4; ++j){
      int tok = tg*16 + lg*4 + j; int tokg = c*64 + tok;
      float qv = bf2f(q_g[(size_t)tok*128 + d]);
      float p = hD[n0l][j]*rv[j]*g0 + qv;
      OH[(size_t)tokg*1024 + bh*128 + d] = f2bf(p*gtv[j]);
    }
  }
}

// ---------------- launch ----------------
extern "C" void kernel_launch(void* const* d_in, const int* in_sizes, int n_in,
                              void* d_out, int out_size, void* d_ws, size_t ws_size,
                              hipStream_t stream) {
  (void)in_sizes; (void)n_in; (void)out_size; (void)ws_size;
  const float* x     = (const float*)d_in[0];
  const float* snw   = (const float*)d_in[1];
  const float* rnw   = (const float*)d_in[2];
  const float* Wq    = (const float*)d_in[3];
  const float* Wk    = (const float*)d_in[4];
  const float* Wv    = (const float*)d_in[5];
  const float* Wstep = (const float*)d_in[6];
  const float* bstep = (const float*)d_in[7];
  const float* Wmom  = (const float*)d_in[8];
  const float* bmom  = (const float*)d_in[9];
  const float* Wdec  = (const float*)d_in[10];
  const float* bdec  = (const float*)d_in[11];
  const float* gateW = (const float*)d_in[12];
  const float* combW = (const float*)d_in[13];
  const float* mw0   = (const float*)d_in[14];
  const float* mw1   = (const float*)d_in[15];
  const float* mg    = (const float*)d_in[16];
  float* out = (float*)d_out;

  char* Wb = (char*)d_ws;
  u16* Qc    = (u16*)(Wb + 0*MB);
  u16* Kc    = (u16*)(Wb + 4*MB);
  u16* Vc    = (u16*)(Wb + 8*MB);
  u16* s_bf  = (u16*)(Wb + 12*MB);
  u16* r_bf  = (u16*)(Wb + 16*MB);
  u16* WqT   = (u16*)(Wb + 20*MB);
  u16* WkT   = (u16*)(Wb + 22*MB);
  u16* WvT   = (u16*)(Wb + 24*MB);
  u16* combT = (u16*)(Wb + 26*MB);
  u16* w0L   = (u16*)(Wb + 28*MB);
  u16* w1L   = (u16*)(Wb + 29*MB);
  u16* w1bL  = (u16*)(Wb + 30*MB);
  u16* OH    = (u16*)(Wb + 31*MB);
  u16* SW0   = (u16*)(Wb + 35*MB);
  u16* SW1   = (u16*)(Wb + 67*MB);
  u16* W0C   = (u16*)(Wb + 99*MB);
  u16* W1C   = (u16*)(Wb + 131*MB);
  float* pooled = (float*)(Wb + 163*MB);
  float* lrc    = (float*)(Wb + 163*MB + 131072);
  float* momb   = (float*)(Wb + 163*MB + 196608);
  float* decb   = (float*)(Wb + 163*MB + 197632);
  float* gate   = (float*)(Wb + 163*MB + 198656);
  float* SG     = (float*)(Wb + 163*MB + 264192);
  float* GC     = (float*)(Wb + 163*MB + 395264);

  hipFuncSetAttribute((const void*)k_grad, hipFuncAttributeMaxDynamicSharedMemorySize, 163840);
  hipFuncSetAttribute((const void*)k_retr, hipFuncAttributeMaxDynamicSharedMemorySize, 66560);

  k_rmsnorm<<<2048, 256, 0, stream>>>(x, snw, rnw, s_bf, r_bf);
  k_pool<<<dim3(32,4), 256, 0, stream>>>(s_bf, pooled);
  k_lrgate<<<512, 256, 0, stream>>>(s_bf, r_bf, Wstep, bstep, gateW, lrc, gate);
  k_momdec<<<32, 64, 0, stream>>>(pooled, Wmom, bmom, Wdec, bdec, momb, decb);
  k_trf4<<<dim3(32,32,4), 256, 0, stream>>>(Wq, Wk, Wv, combW, WqT, WkT, WvT, combT);
  k_packw<<<dim3(256,3,8), 256, 0, stream>>>(mw0, mw1, w0L, w1L, w1bL);
  k_gemm3<<<dim3(32,16,3), 256, 0, stream>>>(s_bf, r_bf, WkT, WvT, WqT, Kc, Vc, Qc);
  k_grad<<<dim3(32,8), 512, 163840, stream>>>(Kc, Vc, lrc, w0L, w1L, w1bL, mg, SW0, SW1, SG);
  k_scan<<<dim3(513,8), 256, 0, stream>>>(w0L, w1L, mg, SW0, SW1, SG, momb, decb, W0C, W1C, GC);
  k_retr<<<dim3(32,8), 512, 66560, stream>>>(Qc, W0C, W1C, GC, gate, OH);
  k_gemm_bf<<<dim3(32,16), 256, 0, stream>>>(OH, combT, (void*)out, 0);
}

// Round 8
// 228.296 us; speedup vs baseline: 1.9023x; 1.1892x over previous
//
#include <hip/hip_runtime.h>
#include <hip/hip_bf16.h>
#include <math.h>

#define NH   8
#define DHD  128
#define HIDN 512
#define CHK  64
#define NCH  32
#define MB   1048576ull

typedef unsigned short u16;
typedef unsigned int   u32;
typedef short s16x8 __attribute__((ext_vector_type(8)));
typedef float f32x4 __attribute__((ext_vector_type(4)));

#define MFMA(a,b,c) __builtin_amdgcn_mfma_f32_16x16x32_bf16((a),(b),(c),0,0,0)

__device__ __forceinline__ float bf2f(u16 v){ return __uint_as_float(((u32)v) << 16); }
__device__ __forceinline__ u16 f2bf(float f){
  u32 u = __float_as_uint(f);
  u += 0x7fffu + ((u >> 16) & 1u);
  return (u16)(u >> 16);
}
__device__ __forceinline__ u32 pack2(float a, float b){
  return (u32)f2bf(a) | ((u32)f2bf(b) << 16);
}
__device__ __forceinline__ float dot2(u32 a, u32 b){
  return __uint_as_float(a << 16)*__uint_as_float(b << 16)
       + __uint_as_float(a & 0xffff0000u)*__uint_as_float(b & 0xffff0000u);
}
__device__ __forceinline__ float waveRedSum(float v){
  #pragma unroll
  for (int off = 32; off; off >>= 1) v += __shfl_xor(v, off);
  return v;
}
// async global->LDS, 16B per lane; lds base must be wave-uniform
__device__ __forceinline__ void gload16(const void* g, void* l){
  __builtin_amdgcn_global_load_lds(
      (const __attribute__((address_space(1))) u32*)g,
      (__attribute__((address_space(3))) u32*)l, 16, 0, 0);
}
// swizzles
__device__ __forceinline__ int swzb(int row, int colb){ return colb ^ ((row & 7) << 4); }
__device__ __forceinline__ int swza(int row, int colb){
  return colb ^ ((row & 7) << 4) ^ (((row >> 3) & 3) << 5);
}

// Fragment-major weight layouts (1KB contiguous per 16x32 MFMA B-tile, lane l owns bytes l*16):
//  L0  (n=hid 32 tiles, k=d 4 blocks), L1 (n=d 8 tiles, k=hid 16 blocks), L1b (like L0, holds w1)

// ---------------- prep ----------------

__global__ __launch_bounds__(256) void k_rmsnorm(const float* __restrict__ x,
    const float* __restrict__ wst, const float* __restrict__ wrt,
    u16* __restrict__ s_bf, u16* __restrict__ r_bf){
  int row = blockIdx.x, t = threadIdx.x;
  float4 v = ((const float4*)(x + (size_t)row*1024))[t];
  float ss = v.x*v.x + v.y*v.y + v.z*v.z + v.w*v.w;
  ss = waveRedSum(ss);
  __shared__ float red[4];
  int wv = t >> 6, ln = t & 63;
  if (ln == 0) red[wv] = ss;
  __syncthreads();
  float rr = rsqrtf((red[0]+red[1]+red[2]+red[3])*(1.f/1024.f) + 1e-6f);
  float4 a = ((const float4*)wst)[t];
  float4 b = ((const float4*)wrt)[t];
  uint2 so = make_uint2(pack2(v.x*rr*a.x, v.y*rr*a.y), pack2(v.z*rr*a.z, v.w*rr*a.w));
  uint2 ro = make_uint2(pack2(v.x*rr*b.x, v.y*rr*b.y), pack2(v.z*rr*b.z, v.w*rr*b.w));
  *(uint2*)(s_bf + (size_t)row*1024 + t*4) = so;
  *(uint2*)(r_bf + (size_t)row*1024 + t*4) = ro;
}

__global__ __launch_bounds__(256) void k_pool(const u16* __restrict__ s_bf, float* __restrict__ pooled){
  int c = blockIdx.x; int d = blockIdx.y*256 + threadIdx.x;
  float acc = 0.f;
  for (int tt = 0; tt < 64; ++tt) acc += bf2f(s_bf[((size_t)c*64+tt)*1024 + d]);
  pooled[(size_t)c*1024 + d] = acc * (1.f/64.f);
}

// vectorized lr/gate: WsgL [16][1024] bf16 (rows 0-7 = Wstep cols, 8-15 = gateW cols)
__global__ __launch_bounds__(256) void k_lrgate(const u16* __restrict__ s_bf, const u16* __restrict__ r_bf,
    const u16* __restrict__ WsgL, const float* __restrict__ bstep,
    float* __restrict__ lrc, float* __restrict__ gate){
  int wv = threadIdx.x >> 6, ln = threadIdx.x & 63;
  int tok = blockIdx.x*4 + wv;
  const u16* sp = s_bf + (size_t)tok*1024 + ln*16;
  const u16* rp = r_bf + (size_t)tok*1024 + ln*16;
  uint4 s0 = *(const uint4*)sp, s1 = *(const uint4*)(sp+8);
  uint4 r0 = *(const uint4*)rp, r1 = *(const uint4*)(rp+8);
  #pragma unroll 4
  for (int o = 0; o < 16; ++o){
    const u16* wp = WsgL + (size_t)o*1024 + ln*16;
    uint4 w0v = *(const uint4*)wp, w1v = *(const uint4*)(wp+8);
    uint4 a0 = (o < 8) ? s0 : r0, a1 = (o < 8) ? s1 : r1;
    float acc = dot2(a0.x,w0v.x)+dot2(a0.y,w0v.y)+dot2(a0.z,w0v.z)+dot2(a0.w,w0v.w)
              + dot2(a1.x,w1v.x)+dot2(a1.y,w1v.y)+dot2(a1.z,w1v.z)+dot2(a1.w,w1v.w);
    acc = waveRedSum(acc);
    if (ln == 0){
      int h = o & 7;
      if (o < 8){
        float v = 1.f/(1.f+expf(-(acc + bstep[h])));
        lrc[((size_t)h*NCH + (tok>>6))*CHK + (tok&63)] = v;
      } else {
        gate[(size_t)tok*8 + h] = 1.f/(1.f+expf(-acc));
      }
    }
  }
}

__global__ __launch_bounds__(64) void k_momdec(const float* __restrict__ pooled,
    const float* __restrict__ Wmom, const float* __restrict__ bmom,
    const float* __restrict__ Wdec, const float* __restrict__ bdec,
    float* __restrict__ momb, float* __restrict__ decb){
  int c = blockIdx.x, ln = threadIdx.x;
  const float* prow = pooled + (size_t)c*1024;
  for (int o = 0; o < 16; ++o){
    int h = o & 7;
    const float* W = (o < 8) ? Wmom : Wdec;
    float acc = 0.f;
    for (int k = ln; k < 1024; k += 64) acc += prow[k]*W[(size_t)k*8+h];
    acc = waveRedSum(acc);
    if (ln == 0){
      float bb = (o < 8) ? bmom[h] : bdec[h];
      float v = 1.f/(1.f+expf(-(acc+bb)));
      if (o < 8) momb[h*NCH + c] = v; else decb[h*NCH + c] = v;
    }
  }
}

// 4 fused 1024x1024 f32->bf16 transposes
__global__ __launch_bounds__(256) void k_trf4(
    const float* __restrict__ A0, const float* __restrict__ A1,
    const float* __restrict__ A2, const float* __restrict__ A3,
    u16* __restrict__ O0, u16* __restrict__ O1, u16* __restrict__ O2, u16* __restrict__ O3){
  __shared__ u16 tile[32][34];
  int z = blockIdx.z;
  const float* in = (z==0)?A0:(z==1)?A1:(z==2)?A2:A3;
  u16* out = (z==0)?O0:(z==1)?O1:(z==2)?O2:O3;
  int c0 = blockIdx.x*32, r0 = blockIdx.y*32;
  int tx = threadIdx.x & 31, ty = threadIdx.x >> 5;
  #pragma unroll
  for (int k = 0; k < 4; ++k) tile[ty+k*8][tx] = f2bf(in[(size_t)(r0+ty+k*8)*1024 + c0+tx]);
  __syncthreads();
  #pragma unroll
  for (int k = 0; k < 4; ++k) out[(size_t)(c0+ty+k*8)*1024 + r0+tx] = tile[tx][ty+k*8];
}

// pack weights: y=0 w0L, y=1 w1L, y=2 w1bL, y=3 WsgL (h==0 only)
__global__ __launch_bounds__(256) void k_packw(const float* __restrict__ mw0, const float* __restrict__ mw1,
    const float* __restrict__ Wstep, const float* __restrict__ gateW,
    u16* __restrict__ w0L, u16* __restrict__ w1L, u16* __restrict__ w1bL, u16* __restrict__ WsgL){
  int h = blockIdx.z, which = blockIdx.y;
  int i = blockIdx.x*256 + threadIdx.x;
  if (which == 3){
    if (h == 0 && i < 16384){
      int o = i >> 10, k = i & 1023;
      float v = (o < 8) ? Wstep[(size_t)k*8 + o] : gateW[(size_t)k*8 + (o-8)];
      WsgL[i] = f2bf(v);
    }
    return;
  }
  int r = i & 511, blk = i >> 9;
  int lg = r >> 7, lr = (r >> 3) & 15, e = r & 7;
  float v; u16* dst;
  if (which == 0){ int n0 = blk >> 2, ks = blk & 3; int hid = n0*16+lr, d = ks*32+lg*8+e;
    v = mw0[(size_t)h*65536 + (size_t)d*512 + hid]; dst = w0L; }
  else if (which == 1){ int n0 = blk >> 4, ks = blk & 15; int d = n0*16+lr, hid = ks*32+lg*8+e;
    v = mw1[(size_t)h*65536 + (size_t)hid*128 + d]; dst = w1L; }
  else { int n0 = blk >> 2, ks = blk & 3; int hid = n0*16+lr, d = ks*32+lg*8+e;
    v = mw1[(size_t)h*65536 + (size_t)hid*128 + d]; dst = w1bL; }
  dst[(size_t)h*65536 + i] = f2bf(v);
}

// ---------------- MFMA GEMM: 64(M)x128(N) tile, 512 thr, global_load_lds staging ----------------
// A[M][K] bf16, BT[N][K] bf16, K=1024. mode 0: C f32 [M][N]; mode 1: C bf16 chunked [h][c][tok][d]
__device__ __forceinline__ void gemm_body(const u16* __restrict__ A, const u16* __restrict__ BT,
    void* __restrict__ Cp, int mode){
  __shared__ char As[8192];    // [64][64] bf16 linear, rows 128B
  __shared__ char Bs[16384];   // [128][64] linear
  int t = threadIdx.x, l = t & 63, w = t >> 6, lr16 = l & 15, lg = l >> 4;
  int wm = w & 1, wn = w >> 1;
  int bm = blockIdx.x*64, bn = blockIdx.y*128;
  f32x4 acc[2][2];
  #pragma unroll
  for (int mt = 0; mt < 2; ++mt)
    #pragma unroll
    for (int nt = 0; nt < 2; ++nt) acc[mt][nt] = (f32x4){0.f,0.f,0.f,0.f};
  for (int k0 = 0; k0 < 1024; k0 += 64){
    gload16(A  + (size_t)(bm + (t>>3))*1024      + k0 + (t&7)*8, As + w*1024);
    gload16(BT + (size_t)(bn + (t>>3))*1024      + k0 + (t&7)*8, Bs + w*1024);
    gload16(BT + (size_t)(bn + 64 + (t>>3))*1024 + k0 + (t&7)*8, Bs + 8192 + w*1024);
    __syncthreads();
    #pragma unroll
    for (int ks = 0; ks < 2; ++ks){
      s16x8 xa[2], yb[2];
      #pragma unroll
      for (int mt = 0; mt < 2; ++mt){ int row = wm*32 + mt*16 + lr16;
        xa[mt] = *(const s16x8*)(As + row*128 + ks*64 + lg*16); }
      #pragma unroll
      for (int nt = 0; nt < 2; ++nt){ int row = wn*32 + nt*16 + lr16;
        yb[nt] = *(const s16x8*)(Bs + row*128 + ks*64 + lg*16); }
      #pragma unroll
      for (int mt = 0; mt < 2; ++mt)
        #pragma unroll
        for (int nt = 0; nt < 2; ++nt) acc[mt][nt] = MFMA(xa[mt], yb[nt], acc[mt][nt]);
    }
    __syncthreads();
  }
  #pragma unroll
  for (int mt = 0; mt < 2; ++mt)
    #pragma unroll
    for (int nt = 0; nt < 2; ++nt)
      #pragma unroll
      for (int j = 0; j < 4; ++j){
        int row = bm + wm*32 + mt*16 + lg*4 + j;
        int coln = bn + wn*32 + nt*16 + lr16;
        if (mode == 0) ((float*)Cp)[(size_t)row*1024 + coln] = acc[mt][nt][j];
        else { int cI = row>>6, tok = row&63, h = coln>>7, d = coln&127;
          ((u16*)Cp)[((size_t)(h*32+cI)*64 + tok)*128 + d] = f2bf(acc[mt][nt][j]); }
      }
}

__global__ __launch_bounds__(512) void k_gemm_bf(const u16* __restrict__ A, const u16* __restrict__ BT,
    void* __restrict__ Cp, int mode){ gemm_body(A, BT, Cp, mode); }

__global__ __launch_bounds__(512) void k_gemm3(
    const u16* __restrict__ s_bf, const u16* __restrict__ r_bf,
    const u16* __restrict__ WkT, const u16* __restrict__ WvT, const u16* __restrict__ WqT,
    u16* __restrict__ Kc, u16* __restrict__ Vc, u16* __restrict__ Qc){
  int z = blockIdx.z;
  const u16* A = (z==2) ? r_bf : s_bf;
  const u16* BT = (z==0) ? WkT : (z==1) ? WvT : WqT;
  u16* C = (z==0) ? Kc : (z==1) ? Vc : Qc;
  gemm_body(A, BT, (void*)C, 1);
}

// ---------------- fused gradient (512 threads; L-layout coalesced stores) ----------------
__global__ __launch_bounds__(512) void k_grad(
    const u16* __restrict__ Kc, const u16* __restrict__ Vc, const float* __restrict__ lrc,
    const u16* __restrict__ w0L, const u16* __restrict__ w1L, const u16* __restrict__ w1bL,
    const float* __restrict__ mg,
    u16* __restrict__ SW0, u16* __restrict__ SW1, float* __restrict__ SG){
  extern __shared__ char sm[];
  char* a_s   = sm;            // 64KB
  char* upT_s = sm + 65536;    // 64KB
  char* dh_s  = sm + 131072;   // 16KB
  char* dhT_s = sm + 147456;   // 16KB
  char* duT_s = a_s;
  char* kcT_s = upT_s;
  char* stg3  = dh_s;
  float* scr  = (float*)dh_s;

  int c = blockIdx.x, bh = blockIdx.y, t = threadIdx.x;
  size_t bc = (size_t)bh*NCH + c;
  int l = t & 63, w = t >> 6, lr16 = l & 15, lg = l >> 4;
  int tg = w & 3, dhf = w >> 2;
  int tokb = tg*16, tok0 = tokb + lg*4;

  const u16* kc_g = Kc + bc*8192;
  const u16* vc_g = Vc + bc*8192;

  // P2
  s16x8 xk[4];
  #pragma unroll
  for (int k = 0; k < 4; ++k)
    xk[k] = *(const s16x8*)(kc_g + (size_t)(tokb+lr16)*128 + k*32 + lg*8);
  const u16* w0Lh = w0L + (size_t)bh*65536;
  for (int n0h = 0; n0h < 16; ++n0h){
    int n0 = dhf*16 + n0h;
    f32x4 acc = {0.f,0.f,0.f,0.f};
    const u16* yb = w0Lh + (size_t)n0*2048 + l*8;
    #pragma unroll
    for (int k = 0; k < 4; ++k) acc = MFMA(xk[k], *(const s16x8*)(yb + k*512), acc);
    int hid = n0*16 + lr16;
    float upv[4];
    #pragma unroll
    for (int j = 0; j < 4; ++j){
      int tok = tok0 + j;
      float u = acc[j];
      float cdf = 0.5f*(1.f + erff(u*0.70710678118654752f));
      upv[j] = cdf + u*0.3989422804014327f*expf(-0.5f*u*u);
      *(u16*)(a_s + tok*1024 + swza(tok, hid*2)) = f2bf(u*cdf);
    }
    *(uint2*)(upT_s + hid*128 + swzb(hid, tok0*2)) =
        make_uint2(pack2(upv[0], upv[1]), pack2(upv[2], upv[3]));
  }
  __syncthreads();

  // P3
  s16x8 xa[16];
  #pragma unroll
  for (int k = 0; k < 16; ++k){ int row = tokb + lr16;
    xa[k] = *(const s16x8*)(a_s + row*1024 + swza(row, (k*32+lg*8)*2)); }
  const u16* w1Lh = w1L + (size_t)bh*65536;
  f32x4 hD[4];
  #pragma unroll
  for (int n0l = 0; n0l < 4; ++n0l){
    f32x4 acc = {0.f,0.f,0.f,0.f};
    const u16* yb = w1Lh + (size_t)(dhf*4 + n0l)*8192 + l*8;
    #pragma unroll
    for (int k = 0; k < 16; ++k) acc = MFMA(xa[k], *(const s16x8*)(yb + k*512), acc);
    hD[n0l] = acc;
  }
  #pragma unroll
  for (int j = 0; j < 4; ++j){
    float s = 0.f;
    #pragma unroll
    for (int n0l = 0; n0l < 4; ++n0l) s += hD[n0l][j]*hD[n0l][j];
    s += __shfl_xor(s,1); s += __shfl_xor(s,2); s += __shfl_xor(s,4); s += __shfl_xor(s,8);
    if (lr16 == 0) scr[dhf*64 + tok0 + j] = s;
  }
  __syncthreads();
  float rv[4], lrv[4], dotp[4];
  #pragma unroll
  for (int j = 0; j < 4; ++j){
    int tok = tok0 + j;
    float tot = scr[tok] + scr[64 + tok];
    rv[j] = rsqrtf(tot*(1.f/128.f) + 1e-6f);
    lrv[j] = lrc[bc*64 + tok];
    dotp[j] = 0.f;
  }
  float dn[4][4];
  #pragma unroll
  for (int n0l = 0; n0l < 4; ++n0l){
    int d = dhf*64 + n0l*16 + lr16;
    float g0 = mg[(size_t)bh*128 + d];
    float dgav = 0.f;
    #pragma unroll
    for (int j = 0; j < 4; ++j){
      int tok = tok0 + j;
      float h = hD[n0l][j];
      float nrm = h*rv[j];
      float kcv = bf2f(kc_g[(size_t)tok*128 + d]);
      float vcv = bf2f(vc_g[(size_t)tok*128 + d]);
      float p = nrm*g0 + kcv;
      float dp = (2.f/128.f)*lrv[j]*(p - vcv);
      dgav += dp*nrm;
      float dnv = dp*g0;
      dn[n0l][j] = dnv;
      dotp[j] += dnv*h;
    }
    dgav += __shfl_xor(dgav,16); dgav += __shfl_xor(dgav,32);
    if (lg == 0) scr[256 + w*64 + n0l*16 + lr16] = dgav;
  }
  #pragma unroll
  for (int j = 0; j < 4; ++j){
    float dd = dotp[j];
    dd += __shfl_xor(dd,1); dd += __shfl_xor(dd,2); dd += __shfl_xor(dd,4); dd += __shfl_xor(dd,8);
    if (lr16 == 0) scr[128 + dhf*64 + tok0 + j] = dd;
  }
  __syncthreads();
  float dotv[4];
  #pragma unroll
  for (int j = 0; j < 4; ++j){
    int tok = tok0 + j;
    dotv[j] = scr[128 + tok] + scr[128 + 64 + tok];
  }
  if (t < 128){
    int dh2 = t >> 6, dl = t & 63;
    float s = scr[256 + (dh2*4+0)*64 + dl] + scr[256 + (dh2*4+1)*64 + dl]
            + scr[256 + (dh2*4+2)*64 + dl] + scr[256 + (dh2*4+3)*64 + dl];
    SG[bc*128 + t] = -s;
  }
  __syncthreads();
  #pragma unroll
  for (int n0l = 0; n0l < 4; ++n0l){
    int d = dhf*64 + n0l*16 + lr16;
    float dhv[4];
    #pragma unroll
    for (int j = 0; j < 4; ++j){
      int tok = tok0 + j;
      float c3 = rv[j]*rv[j]*rv[j]*(1.f/128.f);
      dhv[j] = rv[j]*dn[n0l][j] - c3*dotv[j]*hD[n0l][j];
      *(u16*)(dh_s + tok*256 + swzb(tok, d*2)) = f2bf(dhv[j]);
    }
    *(uint2*)(dhT_s + d*128 + swzb(d, tok0*2)) =
        make_uint2(pack2(dhv[0], dhv[1]), pack2(dhv[2], dhv[3]));
  }
  __syncthreads();

  // B1 -> SW1 (L1)
  {
    s16x8 yB[4][2];
    #pragma unroll
    for (int n0l = 0; n0l < 4; ++n0l){
      int hid = w*64 + n0l*16 + lr16;
      #pragma unroll
      for (int ks = 0; ks < 2; ++ks){
        s16x8 v;
        #pragma unroll
        for (int e = 0; e < 8; ++e){ int tok = ks*32 + lg*8 + e;
          v[e] = *(const short*)(a_s + tok*1024 + swza(tok, hid*2)); }
        yB[n0l][ks] = v;
      }
    }
    __syncthreads();
    u16* stg = (u16*)(a_s + w*8192);
    #pragma unroll 1
    for (int half = 0; half < 2; ++half){
      #pragma unroll
      for (int mt4 = 0; mt4 < 4; ++mt4){
        int mt = half*4 + mt4; int row = mt*16 + lr16;
        s16x8 xD0 = *(const s16x8*)(dhT_s + row*128 + swzb(row, (lg*8)*2));
        s16x8 xD1 = *(const s16x8*)(dhT_s + row*128 + swzb(row, (32+lg*8)*2));
        #pragma unroll
        for (int n0l = 0; n0l < 4; ++n0l){
          f32x4 acc = {0.f,0.f,0.f,0.f};
          acc = MFMA(xD0, yB[n0l][0], acc);
          acc = MFMA(xD1, yB[n0l][1], acc);
          int base = mt4*1024 + (n0l>>1)*512 + (((n0l*2)+(lr16>>3))&3)*128 + (lr16&7);
          #pragma unroll
          for (int j = 0; j < 4; ++j)
            stg[base + (lg*4+j)*8] = f2bf(-acc[j]);
        }
      }
      asm volatile("s_waitcnt lgkmcnt(0)" ::: "memory");
      #pragma unroll
      for (int mt4 = 0; mt4 < 4; ++mt4){
        int mt = half*4 + mt4;
        u16* gb = SW1 + bc*65536 + (size_t)(mt*16 + w*2)*512;
        s16x8 o0 = *(const s16x8*)(stg + mt4*1024 + l*16);
        s16x8 o1 = *(const s16x8*)(stg + mt4*1024 + l*16 + 8);
        *(s16x8*)(gb + l*16) = o0;
        *(s16x8*)(gb + l*16 + 8) = o1;
      }
    }
  }
  __syncthreads();

  // B2 -> duT
  {
    s16x8 xDh[4][4];
    #pragma unroll
    for (int mt = 0; mt < 4; ++mt){ int row = mt*16 + lr16;
      #pragma unroll
      for (int ks = 0; ks < 4; ++ks)
        xDh[mt][ks] = *(const s16x8*)(dh_s + row*256 + swzb(row, (ks*32+lg*8)*2)); }
    const u16* w1bh = w1bL + (size_t)bh*65536;
    #pragma unroll 2
    for (int n0l = 0; n0l < 4; ++n0l){
      int hid = w*64 + n0l*16 + lr16;
      s16x8 yW[4];
      const u16* xb = w1bh + (size_t)(w*4 + n0l)*2048 + l*8;
      #pragma unroll
      for (int ks = 0; ks < 4; ++ks)
        yW[ks] = *(const s16x8*)(xb + ks*512);
      #pragma unroll
      for (int mt = 0; mt < 4; ++mt){
        f32x4 acc = {0.f,0.f,0.f,0.f};
        #pragma unroll
        for (int ks = 0; ks < 4; ++ks) acc = MFMA(xDh[mt][ks], yW[ks], acc);
        int tk0 = mt*16 + lg*4;
        uint2 ur = *(const uint2*)(upT_s + hid*128 + swzb(hid, tk0*2));
        float u0 = bf2f((u16)(ur.x & 0xffff)), u1 = bf2f((u16)(ur.x >> 16));
        float u2 = bf2f((u16)(ur.y & 0xffff)), u3 = bf2f((u16)(ur.y >> 16));
        *(uint2*)(duT_s + hid*128 + swzb(hid, tk0*2)) =
            make_uint2(pack2(acc[0]*u0, acc[1]*u1), pack2(acc[2]*u2, acc[3]*u3));
      }
    }
  }
  __syncthreads();

  // kcT
  #pragma unroll
  for (int i = 0; i < 2; ++i){
    int idx = i*512 + t;
    int tok = idx & 63, d0 = (idx >> 6)*8;
    s16x8 kv = *(const s16x8*)(kc_g + (size_t)tok*128 + d0);
    #pragma unroll
    for (int e = 0; e < 8; ++e)
      *(u16*)(kcT_s + (d0+e)*128 + swzb(d0+e, tok*2)) = kv[e];
  }
  __syncthreads();

  // B3 -> SW0 (L0)
  {
    s16x8 yK[8][2];
    #pragma unroll
    for (int n0 = 0; n0 < 8; ++n0){
      int d = n0*16 + lr16;
      #pragma unroll
      for (int ks = 0; ks < 2; ++ks)
        yK[n0][ks] = *(const s16x8*)(kcT_s + d*128 + swzb(d, (ks*32+lg*8)*2));
    }
    u16* stg = (u16*)(stg3 + w*4096);
    #pragma unroll 1
    for (int mi = 0; mi < 4; ++mi){
      int hid = w*64 + mi*16 + lr16;
      s16x8 xU0 = *(const s16x8*)(duT_s + hid*128 + swzb(hid, (lg*8)*2));
      s16x8 xU1 = *(const s16x8*)(duT_s + hid*128 + swzb(hid, (32+lg*8)*2));
      #pragma unroll
      for (int n0 = 0; n0 < 8; ++n0){
        f32x4 acc = {0.f,0.f,0.f,0.f};
        acc = MFMA(xU0, yK[n0][0], acc);
        acc = MFMA(xU1, yK[n0][1], acc);
        int base = (n0>>1)*512 + (((n0*2)+(lr16>>3))&3)*128 + (lr16&7);
        #pragma unroll
        for (int j = 0; j < 4; ++j)
          stg[base + (lg*4+j)*8] = f2bf(-acc[j]);
      }
      asm volatile("s_waitcnt lgkmcnt(0)" ::: "memory");
      u16* gb = SW0 + bc*65536 + (size_t)(w*4 + mi)*2048;
      #pragma unroll
      for (int q = 0; q < 4; ++q){
        s16x8 o = *(const s16x8*)(stg + l*32 + q*8);
        *(s16x8*)(gb + l*32 + q*8) = o;
      }
    }
  }
}

// ---------------- scans ----------------
__global__ __launch_bounds__(256) void k_scan(
    const u16* __restrict__ w0L, const u16* __restrict__ w1L, const float* __restrict__ mg,
    const u16* __restrict__ SW0, const u16* __restrict__ SW1, const float* __restrict__ SG,
    const float* __restrict__ momb, const float* __restrict__ decb,
    u16* __restrict__ W0C, u16* __restrict__ W1C, float* __restrict__ GC){
  int bh = blockIdx.y;
  int e = blockIdx.x*256 + threadIdx.x;
  const float* momp = momb + bh*NCH;
  const float* decp = decb + bh*NCH;
  float m = 0.f, Wv;
  if (e < 65536){
    Wv = bf2f(w0L[(size_t)bh*65536 + e]);
    const u16* su = SW0 + (size_t)bh*NCH*65536 + e;
    u16* outp = W0C + (size_t)bh*NCH*65536 + e;
    for (int c = 0; c < NCH; ++c){
      outp[(size_t)c*65536] = f2bf(Wv);
      m = momp[c]*m + bf2f(su[(size_t)c*65536]);
      Wv = (1.f - decp[c])*Wv + m;
    }
  } else if (e < 131072){
    int e2 = e - 65536;
    Wv = bf2f(w1L[(size_t)bh*65536 + e2]);
    const u16* su = SW1 + (size_t)bh*NCH*65536 + e2;
    u16* outp = W1C + (size_t)bh*NCH*65536 + e2;
    for (int c = 0; c < NCH; ++c){
      outp[(size_t)c*65536] = f2bf(Wv);
      m = momp[c]*m + bf2f(su[(size_t)c*65536]);
      Wv = (1.f - decp[c])*Wv + m;
    }
  } else if (e < 131200){
    int e3 = e - 131072;
    Wv = mg[(size_t)bh*128 + e3];
    const float* su = SG + (size_t)bh*NCH*128 + e3;
    float* outp = GC + (size_t)bh*NCH*128 + e3;
    for (int c = 0; c < NCH; ++c){
      outp[(size_t)c*128] = Wv;
      m = momp[c]*m + su[(size_t)c*128];
      Wv = (1.f - decp[c])*Wv + m;
    }
  }
}

// ---------------- retrieval ----------------
__global__ __launch_bounds__(512) void k_retr(
    const u16* __restrict__ Qc, const u16* __restrict__ W0C, const u16* __restrict__ W1C,
    const float* __restrict__ GC, const float* __restrict__ gate, u16* __restrict__ OH){
  extern __shared__ char sm[];
  char* a_s = sm;
  float* scr = (float*)(sm + 65536);
  int c = blockIdx.x, bh = blockIdx.y, t = threadIdx.x;
  size_t bc = (size_t)bh*NCH + c;
  int l = t & 63, w = t >> 6, lr16 = l & 15, lg = l >> 4;
  int tg = w & 3, dhf = w >> 2;
  const u16* q_g = Qc + bc*8192;

  s16x8 xq[4];
  #pragma unroll
  for (int k = 0; k < 4; ++k)
    xq[k] = *(const s16x8*)(q_g + (size_t)(tg*16+lr16)*128 + k*32 + lg*8);
  const u16* w0c = W0C + bc*65536;
  for (int n0h = 0; n0h < 16; ++n0h){
    int n0 = dhf*16 + n0h;
    f32x4 acc = {0.f,0.f,0.f,0.f};
    const u16* yb = w0c + (size_t)n0*2048 + l*8;
    #pragma unroll
    for (int k = 0; k < 4; ++k) acc = MFMA(xq[k], *(const s16x8*)(yb + k*512), acc);
    int hid = n0*16 + lr16;
    #pragma unroll
    for (int j = 0; j < 4; ++j){
      int tok = tg*16 + lg*4 + j;
      float u = acc[j];
      float av = u*0.5f*(1.f + erff(u*0.70710678118654752f));
      *(u16*)(a_s + tok*1024 + swza(tok, hid*2)) = f2bf(av);
    }
  }
  __syncthreads();
  s16x8 xa[16];
  #pragma unroll
  for (int k = 0; k < 16; ++k){ int row = tg*16 + lr16;
    xa[k] = *(const s16x8*)(a_s + row*1024 + swza(row, (k*32+lg*8)*2)); }
  const u16* w1c = W1C + bc*65536;
  f32x4 hD[4];
  #pragma unroll
  for (int n0l = 0; n0l < 4; ++n0l){
    f32x4 acc = {0.f,0.f,0.f,0.f};
    const u16* yb = w1c + (size_t)(dhf*4 + n0l)*8192 + l*8;
    #pragma unroll
    for (int k = 0; k < 16; ++k) acc = MFMA(xa[k], *(const s16x8*)(yb + k*512), acc);
    hD[n0l] = acc;
  }
  #pragma unroll
  for (int j = 0; j < 4; ++j){
    float s = 0.f;
    #pragma unroll
    for (int n0l = 0; n0l < 4; ++n0l) s += hD[n0l][j]*hD[n0l][j];
    s += __shfl_xor(s,1); s += __shfl_xor(s,2); s += __shfl_xor(s,4); s += __shfl_xor(s,8);
    if (lr16 == 0) scr[dhf*64 + tg*16 + lg*4 + j] = s;
  }
  __syncthreads();
  float rv[4], gtv[4];
  #pragma unroll
  for (int j = 0; j < 4; ++j){
    int tok = tg*16 + lg*4 + j;
    rv[j] = rsqrtf((scr[tok] + scr[64 + tok])*(1.f/128.f) + 1e-6f);
    gtv[j] = gate[(size_t)(c*64 + tok)*8 + bh];
  }
  #pragma unroll
  for (int n0l = 0; n0l < 4; ++n0l){
    int d = dhf*64 + n0l*16 + lr16;
    float g0 = GC[bc*128 + d];
    #pragma unroll
    for (int j = 0; j < 4; ++j){
      int tok = tg*16 + lg*4 + j; int tokg = c*64 + tok;
      float qv = bf2f(q_g[(size_t)tok*128 + d]);
      float p = hD[n0l][j]*rv[j]*g0 + qv;
      OH[(size_t)tokg*1024 + bh*128 + d] = f2bf(p*gtv[j]);
    }
  }
}

// ---------------- launch ----------------
extern "C" void kernel_launch(void* const* d_in, const int* in_sizes, int n_in,
                              void* d_out, int out_size, void* d_ws, size_t ws_size,
                              hipStream_t stream) {
  (void)in_sizes; (void)n_in; (void)out_size; (void)ws_size;
  const float* x     = (const float*)d_in[0];
  const float* snw   = (const float*)d_in[1];
  const float* rnw   = (const float*)d_in[2];
  const float* Wq    = (const float*)d_in[3];
  const float* Wk    = (const float*)d_in[4];
  const float* Wv    = (const float*)d_in[5];
  const float* Wstep = (const float*)d_in[6];
  const float* bstep = (const float*)d_in[7];
  const float* Wmom  = (const float*)d_in[8];
  const float* bmom  = (const float*)d_in[9];
  const float* Wdec  = (const float*)d_in[10];
  const float* bdec  = (const float*)d_in[11];
  const float* gateW = (const float*)d_in[12];
  const float* combW = (const float*)d_in[13];
  const float* mw0   = (const float*)d_in[14];
  const float* mw1   = (const float*)d_in[15];
  const float* mg    = (const float*)d_in[16];
  float* out = (float*)d_out;

  char* Wb = (char*)d_ws;
  u16* Qc    = (u16*)(Wb + 0*MB);
  u16* Kc    = (u16*)(Wb + 4*MB);
  u16* Vc    = (u16*)(Wb + 8*MB);
  u16* s_bf  = (u16*)(Wb + 12*MB);
  u16* r_bf  = (u16*)(Wb + 16*MB);
  u16* WqT   = (u16*)(Wb + 20*MB);
  u16* WkT   = (u16*)(Wb + 22*MB);
  u16* WvT   = (u16*)(Wb + 24*MB);
  u16* combT = (u16*)(Wb + 26*MB);
  u16* w0L   = (u16*)(Wb + 28*MB);
  u16* w1L   = (u16*)(Wb + 29*MB);
  u16* w1bL  = (u16*)(Wb + 30*MB);
  u16* OH    = (u16*)(Wb + 31*MB);
  u16* SW0   = (u16*)(Wb + 35*MB);
  u16* SW1   = (u16*)(Wb + 67*MB);
  u16* W0C   = (u16*)(Wb + 99*MB);
  u16* W1C   = (u16*)(Wb + 131*MB);
  float* pooled = (float*)(Wb + 163*MB);
  float* lrc    = (float*)(Wb + 163*MB + 131072);
  float* momb   = (float*)(Wb + 163*MB + 196608);
  float* decb   = (float*)(Wb + 163*MB + 197632);
  float* gate   = (float*)(Wb + 163*MB + 198656);
  float* SG     = (float*)(Wb + 163*MB + 264192);
  float* GC     = (float*)(Wb + 163*MB + 395264);
  u16* WsgL  = (u16*)(Wb + 163*MB + 526336);

  hipFuncSetAttribute((const void*)k_grad, hipFuncAttributeMaxDynamicSharedMemorySize, 163840);
  hipFuncSetAttribute((const void*)k_retr, hipFuncAttributeMaxDynamicSharedMemorySize, 66560);

  k_rmsnorm<<<2048, 256, 0, stream>>>(x, snw, rnw, s_bf, r_bf);
  k_pool<<<dim3(32,4), 256, 0, stream>>>(s_bf, pooled);
  k_packw<<<dim3(256,4,8), 256, 0, stream>>>(mw0, mw1, Wstep, gateW, w0L, w1L, w1bL, WsgL);
  k_lrgate<<<512, 256, 0, stream>>>(s_bf, r_bf, WsgL, bstep, lrc, gate);
  k_momdec<<<32, 64, 0, stream>>>(pooled, Wmom, bmom, Wdec, bdec, momb, decb);
  k_trf4<<<dim3(32,32,4), 256, 0, stream>>>(Wq, Wk, Wv, combW, WqT, WkT, WvT, combT);
  k_gemm3<<<dim3(32,8,3), 512, 0, stream>>>(s_bf, r_bf, WkT, WvT, WqT, Kc, Vc, Qc);
  k_grad<<<dim3(32,8), 512, 163840, stream>>>(Kc, Vc, lrc, w0L, w1L, w1bL, mg, SW0, SW1, SG);
  k_scan<<<dim3(513,8), 256, 0, stream>>>(w0L, w1L, mg, SW0, SW1, SG, momb, decb, W0C, W1C, GC);
  k_retr<<<dim3(32,8), 512, 66560, stream>>>(Qc, W0C, W1C, GC, gate, OH);
  k_gemm_bf<<<dim3(32,8), 512, 0, stream>>>(OH, combT, (void*)out, 0);
}